// Round 1
// baseline (707.048 us; speedup 1.0000x reference)
//
#include <hip/hip_runtime.h>

#define NN 50000
#define NE 800000
#define D 128
#define NH 4

__device__ __forceinline__ float lrelu(float x){ return x > 0.f ? x : 0.2f*x; }

// ---------- CSR build ----------

__global__ void k_hist(const int* __restrict__ dst, int* __restrict__ counts){
  int i = blockIdx.x*256 + threadIdx.x;
  if (i < NE) atomicAdd(&counts[dst[i]], 1);
}

__global__ void k_scan_a(const int* __restrict__ counts, int* __restrict__ partial){
  __shared__ int sd[256];
  int t = threadIdx.x;
  int base = blockIdx.x*1024 + t*4;
  int s = 0;
  #pragma unroll
  for (int k=0;k<4;k++){ int i = base+k; if (i<NN) s += counts[i]; }
  sd[t]=s; __syncthreads();
  for (int off=128; off>=1; off>>=1){
    if (t<off) sd[t]+=sd[t+off];
    __syncthreads();
  }
  if (t==0) partial[blockIdx.x]=sd[0];
}

__global__ void k_scan_b(int* __restrict__ partial, int nb){
  if (threadIdx.x==0 && blockIdx.x==0){
    int run=0;
    for (int i=0;i<nb;i++){ int v=partial[i]; partial[i]=run; run+=v; }
  }
}

__global__ void k_scan_c(const int* __restrict__ counts, const int* __restrict__ partial,
                         int* __restrict__ offs, int* __restrict__ cursor){
  __shared__ int sd[256];
  int t = threadIdx.x;
  int base = blockIdx.x*1024 + t*4;
  int c0=0,c1=0,c2=0,c3=0;
  if (base+0<NN) c0=counts[base+0];
  if (base+1<NN) c1=counts[base+1];
  if (base+2<NN) c2=counts[base+2];
  if (base+3<NN) c3=counts[base+3];
  int tot = c0+c1+c2+c3;
  sd[t]=tot; __syncthreads();
  for (int off=1; off<256; off<<=1){
    int add = (t>=off)? sd[t-off]:0;
    __syncthreads();
    sd[t]+=add;
    __syncthreads();
  }
  int excl = sd[t]-tot + partial[blockIdx.x];
  int o0=excl, o1=o0+c0, o2=o1+c1, o3=o2+c2;
  if (base+0<NN){ offs[base+0]=o0; cursor[base+0]=o0; }
  if (base+1<NN){ offs[base+1]=o1; cursor[base+1]=o1; }
  if (base+2<NN){ offs[base+2]=o2; cursor[base+2]=o2; }
  if (base+3<NN){ offs[base+3]=o3; cursor[base+3]=o3; }
  if (blockIdx.x==0 && t==0) offs[NN]=NE;
}

__global__ void k_scatter(const int* __restrict__ src, const int* __restrict__ dst,
                          const float* __restrict__ w, int* __restrict__ cursor,
                          int* __restrict__ src_s, float* __restrict__ w_s){
  int i = blockIdx.x*256 + threadIdx.x;
  if (i<NE){
    int d = dst[i];
    int pos = atomicAdd(&cursor[d],1);
    src_s[pos]=src[i];
    w_s[pos]=w[i];
  }
}

// ---------- weighted aggregation: out[v] = hin[v] + sum_{e:dst=v} w_e * hin[src_e] ----------
// one wave (64 lanes) per node, lane handles 2 columns (float2)
__global__ void k_wagg(const float* __restrict__ hin, const int* __restrict__ offs,
                       const int* __restrict__ src_s, const float* __restrict__ w_s,
                       float* __restrict__ hout){
  int node = (blockIdx.x*256 + threadIdx.x)>>6;
  int lane = threadIdx.x & 63;
  if (node>=NN) return;
  int beg=offs[node], end=offs[node+1];
  int c = lane*2;
  float2 acc = *(const float2*)&hin[(size_t)node*D + c];
  for (int j=beg;j<end;j++){
    int s = src_s[j];
    float w = w_s[j];
    float2 x = *(const float2*)&hin[(size_t)s*D + c];
    acc.x = fmaf(x.x, w, acc.x);
    acc.y = fmaf(x.y, w, acc.y);
  }
  *(float2*)&hout[(size_t)node*D + c] = acc;
}

// ---------- GEMM: feat = X @ W (128x128), plus el/er head-dot products ----------
// block = 128 threads (thread t owns output column t), 32 rows per block.
__global__ __launch_bounds__(128) void k_gemm(const float* __restrict__ X, const float* __restrict__ W,
    const float* __restrict__ al, const float* __restrict__ ar,
    float* __restrict__ feat, float* __restrict__ el, float* __restrict__ er){
  __shared__ float sX[32][128];
  int t = threadIdx.x;
  int row0 = blockIdx.x*32;
  for (int i=t; i<32*128; i+=128){
    int r=i>>7, c=i&127;
    int gr = row0+r;
    sX[r][c] = (gr<NN)? X[(size_t)gr*D + c] : 0.f;
  }
  __syncthreads();
  float acc[32];
  #pragma unroll
  for (int r=0;r<32;r++) acc[r]=0.f;
  for (int k=0;k<128;k+=2){
    float w0 = W[k*128 + t];
    float w1 = W[(k+1)*128 + t];
    #pragma unroll
    for (int r=0;r<32;r++){
      float2 x = *(const float2*)&sX[r][k];
      acc[r] = fmaf(x.x, w0, acc[r]);
      acc[r] = fmaf(x.y, w1, acc[r]);
    }
  }
  float alv = al[t], arv = ar[t];
  int head = t>>5;
  for (int r=0;r<32;r++){
    int gr = row0+r;
    if (gr>=NN) break;
    float a = acc[r];
    feat[(size_t)gr*D + t] = a;
    float e_l = a*alv, e_r = a*arv;
    #pragma unroll
    for (int off=16; off>=1; off>>=1){
      e_l += __shfl_xor(e_l, off);
      e_r += __shfl_xor(e_r, off);
    }
    if ((t&31)==0){
      el[gr*NH + head] = e_l;
      er[gr*NH + head] = e_r;
    }
  }
}

// ---------- GAT edge-softmax + aggregation, one wave per dst node ----------
// FINAL=0: out = relu(rst + b + resid);  FINAL=1: out = rst + b
template<int FINAL>
__global__ void k_gat(const float* __restrict__ feat, const float* __restrict__ el,
                      const float* __restrict__ er, const float* __restrict__ bias,
                      const int* __restrict__ offs, const int* __restrict__ src_s,
                      const float* __restrict__ resid, float* __restrict__ out){
  int node = (blockIdx.x*256 + threadIdx.x)>>6;
  int lane = threadIdx.x & 63;
  if (node>=NN) return;
  int beg=offs[node], end=offs[node+1];
  int c = lane*2;
  int head = c>>5;
  float er0=er[node*NH+0], er1=er[node*NH+1], er2=er[node*NH+2], er3=er[node*NH+3];
  // pass A: per-head max over incoming edges (lanes split edges, then wave-reduce)
  float m0=-1e30f,m1=-1e30f,m2=-1e30f,m3=-1e30f;
  for (int j=beg+lane; j<end; j+=64){
    int s = src_s[j];
    float4 e_l = *(const float4*)&el[(size_t)s*NH];
    m0 = fmaxf(m0, lrelu(e_l.x+er0));
    m1 = fmaxf(m1, lrelu(e_l.y+er1));
    m2 = fmaxf(m2, lrelu(e_l.z+er2));
    m3 = fmaxf(m3, lrelu(e_l.w+er3));
  }
  #pragma unroll
  for (int off=32; off>=1; off>>=1){
    m0 = fmaxf(m0, __shfl_xor(m0, off));
    m1 = fmaxf(m1, __shfl_xor(m1, off));
    m2 = fmaxf(m2, __shfl_xor(m2, off));
    m3 = fmaxf(m3, __shfl_xor(m3, off));
  }
  // pass B: accumulate feat[src]*exp(e-m); divide by sum at the end
  float s0=0.f,s1=0.f,s2=0.f,s3=0.f;
  float ax=0.f, ay=0.f;
  for (int j=beg;j<end;j++){
    int s = src_s[j];
    float4 e_l = *(const float4*)&el[(size_t)s*NH];
    float e0 = expf(lrelu(e_l.x+er0)-m0);
    float e1 = expf(lrelu(e_l.y+er1)-m1);
    float e2 = expf(lrelu(e_l.z+er2)-m2);
    float e3 = expf(lrelu(e_l.w+er3)-m3);
    s0+=e0; s1+=e1; s2+=e2; s3+=e3;
    float eh = head==0?e0 : head==1?e1 : head==2?e2 : e3;
    float2 f = *(const float2*)&feat[(size_t)s*D + c];
    ax = fmaf(f.x, eh, ax);
    ay = fmaf(f.y, eh, ay);
  }
  float sh = head==0?s0 : head==1?s1 : head==2?s2 : s3;
  float rx, ry;
  if (end>beg){ rx = ax/sh; ry = ay/sh; } else { rx=0.f; ry=0.f; }
  rx += bias[c]; ry += bias[c+1];
  if (!FINAL){
    rx += resid[(size_t)node*D + c];
    ry += resid[(size_t)node*D + c+1];
    rx = fmaxf(rx, 0.f);
    ry = fmaxf(ry, 0.f);
  }
  float2 o; o.x=rx; o.y=ry;
  *(float2*)&out[(size_t)node*D + c] = o;
}

extern "C" void kernel_launch(void* const* d_in, const int* in_sizes, int n_in,
                              void* d_out, int out_size, void* d_ws, size_t ws_size,
                              hipStream_t stream){
  const float* in_feat = (const float*)d_in[0];
  const float* ew  = (const float*)d_in[1];
  const float* W0  = (const float*)d_in[2];
  const float* al0 = (const float*)d_in[3];
  const float* ar0 = (const float*)d_in[4];
  const float* b0  = (const float*)d_in[5];
  const float* W1  = (const float*)d_in[6];
  const float* al1 = (const float*)d_in[7];
  const float* ar1 = (const float*)d_in[8];
  const float* b1  = (const float*)d_in[9];
  const int* src = (const int*)d_in[10];
  const int* dst = (const int*)d_in[11];
  float* out = (float*)d_out;

  char* p = (char*)d_ws;
  auto alloc = [&](size_t b)->void*{ void* r=(void*)p; p += ((b+255)&~(size_t)255); return r; };
  int*   counts = (int*)alloc((size_t)NN*4);
  int*   offs   = (int*)alloc((size_t)(NN+1)*4);
  int*   cursor = (int*)alloc((size_t)NN*4);
  int*   partial= (int*)alloc(64*4);
  int*   src_s  = (int*)alloc((size_t)NE*4);
  float* w_s    = (float*)alloc((size_t)NE*4);
  float* bufA   = (float*)alloc((size_t)NN*D*4);
  float* bufB   = (float*)alloc((size_t)NN*D*4);
  float* bufC   = (float*)alloc((size_t)NN*D*4);
  float* el     = (float*)alloc((size_t)NN*NH*4);
  float* er     = (float*)alloc((size_t)NN*NH*4);

  hipMemsetAsync(counts, 0, (size_t)NN*4, stream);
  k_hist<<<(NE+255)/256, 256, 0, stream>>>(dst, counts);
  int nb = (NN+1023)/1024; // 49
  k_scan_a<<<nb,256,0,stream>>>(counts, partial);
  k_scan_b<<<1,64,0,stream>>>(partial, nb);
  k_scan_c<<<nb,256,0,stream>>>(counts, partial, offs, cursor);
  k_scatter<<<(NE+255)/256,256,0,stream>>>(src, dst, ew, cursor, src_s, w_s);

  int nwb = (NN*64 + 255)/256; // 12500 blocks, 4 waves (nodes) per block

  // layer 0
  k_wagg<<<nwb,256,0,stream>>>(in_feat, offs, src_s, w_s, bufA);
  k_gemm<<<(NN+31)/32,128,0,stream>>>(bufA, W0, al0, ar0, bufB, el, er);
  k_gat<0><<<nwb,256,0,stream>>>(bufB, el, er, b0, offs, src_s, in_feat, bufC);

  // layer 1
  k_wagg<<<nwb,256,0,stream>>>(bufC, offs, src_s, w_s, bufA);
  k_gemm<<<(NN+31)/32,128,0,stream>>>(bufA, W1, al1, ar1, bufB, el, er);
  k_gat<1><<<nwb,256,0,stream>>>(bufB, el, er, b1, offs, src_s, nullptr, out);
}

// Round 2
// 475.130 us; speedup vs baseline: 1.4881x; 1.4881x over previous
//
#include <hip/hip_runtime.h>

#define NN 50000
#define NE 800000
#define D 128
#define NH 4

__device__ __forceinline__ float lrelu(float x){ return x > 0.f ? x : 0.2f*x; }
__device__ __forceinline__ float sel4(int h, float4 v){
  float r = v.x;
  r = (h==1)? v.y : r;
  r = (h==2)? v.z : r;
  r = (h==3)? v.w : r;
  return r;
}

// ---------- CSR build ----------

__global__ void k_hist(const int* __restrict__ dst, int* __restrict__ counts){
  int i = blockIdx.x*256 + threadIdx.x;
  if (i < NE) atomicAdd(&counts[dst[i]], 1);
}

__global__ void k_scan_a(const int* __restrict__ counts, int* __restrict__ partial){
  __shared__ int sd[256];
  int t = threadIdx.x;
  int base = blockIdx.x*1024 + t*4;
  int s = 0;
  #pragma unroll
  for (int k=0;k<4;k++){ int i = base+k; if (i<NN) s += counts[i]; }
  sd[t]=s; __syncthreads();
  for (int off=128; off>=1; off>>=1){
    if (t<off) sd[t]+=sd[t+off];
    __syncthreads();
  }
  if (t==0) partial[blockIdx.x]=sd[0];
}

__global__ void k_scan_b(int* __restrict__ partial, int nb){
  if (threadIdx.x==0 && blockIdx.x==0){
    int run=0;
    for (int i=0;i<nb;i++){ int v=partial[i]; partial[i]=run; run+=v; }
  }
}

__global__ void k_scan_c(const int* __restrict__ counts, const int* __restrict__ partial,
                         int* __restrict__ offs, int* __restrict__ cursor){
  __shared__ int sd[256];
  int t = threadIdx.x;
  int base = blockIdx.x*1024 + t*4;
  int c0=0,c1=0,c2=0,c3=0;
  if (base+0<NN) c0=counts[base+0];
  if (base+1<NN) c1=counts[base+1];
  if (base+2<NN) c2=counts[base+2];
  if (base+3<NN) c3=counts[base+3];
  int tot = c0+c1+c2+c3;
  sd[t]=tot; __syncthreads();
  for (int off=1; off<256; off<<=1){
    int add = (t>=off)? sd[t-off]:0;
    __syncthreads();
    sd[t]+=add;
    __syncthreads();
  }
  int excl = sd[t]-tot + partial[blockIdx.x];
  int o0=excl, o1=o0+c0, o2=o1+c1, o3=o2+c2;
  if (base+0<NN){ offs[base+0]=o0; cursor[base+0]=o0; }
  if (base+1<NN){ offs[base+1]=o1; cursor[base+1]=o1; }
  if (base+2<NN){ offs[base+2]=o2; cursor[base+2]=o2; }
  if (base+3<NN){ offs[base+3]=o3; cursor[base+3]=o3; }
  if (blockIdx.x==0 && t==0) offs[NN]=NE;
}

__global__ void k_scatter(const int* __restrict__ src, const int* __restrict__ dst,
                          const float* __restrict__ w, int* __restrict__ cursor,
                          int* __restrict__ src_s, float* __restrict__ w_s){
  int i = blockIdx.x*256 + threadIdx.x;
  if (i<NE){
    int d = dst[i];
    int pos = atomicAdd(&cursor[d],1);
    src_s[pos]=src[i];
    w_s[pos]=w[i];
  }
}

// ---------- weighted aggregation: out[v] = hin[v] + sum_{e:dst=v} w_e * hin[src_e] ----------
// one wave per node; src/w preloaded strided, broadcast via shuffles
__global__ void k_wagg(const float* __restrict__ hin, const int* __restrict__ offs,
                       const int* __restrict__ src_s, const float* __restrict__ w_s,
                       float* __restrict__ hout){
  int node = (blockIdx.x*256 + threadIdx.x)>>6;
  int lane = threadIdx.x & 63;
  if (node>=NN) return;
  int beg=offs[node], end=offs[node+1];
  int c = lane*2;
  float2 acc = *(const float2*)&hin[(size_t)node*D + c];
  for (int cb=beg; cb<end; cb+=64){
    int n = end-cb; if (n>64) n=64;
    int idx = cb + (lane<n ? lane : 0);
    int sp = src_s[idx];
    float wp = w_s[idx];
    for (int j=0;j<n;j++){
      int s = __shfl(sp, j);
      float w = __shfl(wp, j);
      const float2 x = *(const float2*)&hin[(size_t)s*D + c];
      acc.x = fmaf(x.x, w, acc.x);
      acc.y = fmaf(x.y, w, acc.y);
    }
  }
  *(float2*)&hout[(size_t)node*D + c] = acc;
}

// ---------- GEMM: feat = X @ W (128x128), plus el/er head-dot products ----------
// 256 threads, 128-row tile; thread: 16 rows (rh=t>>5), 4 cols {c0,c0+32,c0+64,c0+96} (one per head)
__global__ __launch_bounds__(256) void k_gemm(const float* __restrict__ X, const float* __restrict__ W,
    const float* __restrict__ al, const float* __restrict__ ar,
    float* __restrict__ feat, float4* __restrict__ el4, float4* __restrict__ er4){
  __shared__ float sX[128][128];
  int t = threadIdx.x;
  int row0 = blockIdx.x*128;
  for (int i=t; i<128*32; i+=256){
    int r = i>>5, c4 = (i&31)<<2;
    int gr = row0 + r;
    float4 v = make_float4(0.f,0.f,0.f,0.f);
    if (gr<NN) v = *(const float4*)&X[(size_t)gr*D + c4];
    *(float4*)&sX[r][c4] = v;
  }
  __syncthreads();
  int c0 = t & 31;
  int rh = t >> 5;
  float acc[16][4];
  #pragma unroll
  for (int r=0;r<16;r++){
    #pragma unroll
    for (int j=0;j<4;j++) acc[r][j]=0.f;
  }
  for (int k=0;k<128;k+=4){
    float w[4][4];
    #pragma unroll
    for (int kk=0;kk<4;kk++){
      #pragma unroll
      for (int j=0;j<4;j++) w[kk][j] = W[(size_t)(k+kk)*128 + c0 + 32*j];
    }
    #pragma unroll
    for (int r=0;r<16;r++){
      float4 x = *(const float4*)&sX[rh*16+r][k];
      #pragma unroll
      for (int j=0;j<4;j++){
        acc[r][j] = fmaf(x.x, w[0][j], acc[r][j]);
        acc[r][j] = fmaf(x.y, w[1][j], acc[r][j]);
        acc[r][j] = fmaf(x.z, w[2][j], acc[r][j]);
        acc[r][j] = fmaf(x.w, w[3][j], acc[r][j]);
      }
    }
  }
  float alv[4], arv[4];
  #pragma unroll
  for (int j=0;j<4;j++){ alv[j]=al[c0+32*j]; arv[j]=ar[c0+32*j]; }
  for (int r=0;r<16;r++){
    int gr = row0 + rh*16 + r;
    if (gr>=NN) break;
    float e[4], f[4];
    #pragma unroll
    for (int j=0;j<4;j++){
      feat[(size_t)gr*D + c0 + 32*j] = acc[r][j];
      e[j] = acc[r][j]*alv[j];
      f[j] = acc[r][j]*arv[j];
    }
    #pragma unroll
    for (int off=16; off>=1; off>>=1){
      #pragma unroll
      for (int j=0;j<4;j++){
        e[j] += __shfl_xor(e[j], off);
        f[j] += __shfl_xor(f[j], off);
      }
    }
    if (c0==0){
      el4[gr] = make_float4(e[0],e[1],e[2],e[3]);
      er4[gr] = make_float4(f[0],f[1],f[2],f[3]);
    }
  }
}

// ---------- GAT edge-softmax + aggregation, one wave per dst node ----------
// chunk-of-16 edges: lane l computes exp for (edge l>>2, head l&3) ONCE; FMA loop uses bpermute
template<int FINAL>
__global__ void k_gat(const float* __restrict__ feat, const float4* __restrict__ el4,
                      const float4* __restrict__ er4, const float* __restrict__ bias,
                      const int* __restrict__ offs, const int* __restrict__ src_s,
                      const float* __restrict__ resid, float* __restrict__ out){
  int node = (blockIdx.x*256 + threadIdx.x)>>6;
  int lane = threadIdx.x & 63;
  if (node>=NN) return;
  int beg=offs[node], end=offs[node+1];
  int c = lane*2;
  int h2 = lane>>4;            // head of columns c,c+1
  float4 erv = er4[node];
  // pass A: per-head max of el over incoming srcs (lrelu is monotone: m = lrelu(max el + er))
  float4 mx = make_float4(-3e38f,-3e38f,-3e38f,-3e38f);
  for (int j=beg+lane; j<end; j+=64){
    float4 v = el4[src_s[j]];
    mx.x=fmaxf(mx.x,v.x); mx.y=fmaxf(mx.y,v.y);
    mx.z=fmaxf(mx.z,v.z); mx.w=fmaxf(mx.w,v.w);
  }
  #pragma unroll
  for (int off=32; off>=1; off>>=1){
    mx.x=fmaxf(mx.x,__shfl_xor(mx.x,off));
    mx.y=fmaxf(mx.y,__shfl_xor(mx.y,off));
    mx.z=fmaxf(mx.z,__shfl_xor(mx.z,off));
    mx.w=fmaxf(mx.w,__shfl_xor(mx.w,off));
  }
  float4 m = make_float4(lrelu(mx.x+erv.x), lrelu(mx.y+erv.y),
                         lrelu(mx.z+erv.z), lrelu(mx.w+erv.w));
  int hp = lane & 3;
  float mh  = sel4(hp, m);
  float erh = sel4(hp, erv);
  int eidx = lane>>2;
  float s_acc = 0.f;
  float ax=0.f, ay=0.f;
  for (int cb=beg; cb<end; cb+=16){
    int n = end-cb; if (n>16) n=16;
    int j = cb + (eidx<n ? eidx : 0);
    int sp = src_s[j];
    float4 ev = el4[sp];
    float e = expf(lrelu(sel4(hp,ev) + erh) - mh);
    e = (eidx<n) ? e : 0.f;
    s_acc += e;
    for (int q=0;q<n;q++){
      int sl = q<<2;
      int sj = __shfl(sp, sl);
      float eh = __shfl(e, sl + h2);
      const float2 f = *(const float2*)&feat[(size_t)sj*D + c];
      ax = fmaf(f.x, eh, ax);
      ay = fmaf(f.y, eh, ay);
    }
  }
  s_acc += __shfl_xor(s_acc,4);
  s_acc += __shfl_xor(s_acc,8);
  s_acc += __shfl_xor(s_acc,16);
  s_acc += __shfl_xor(s_acc,32);
  float sh = __shfl(s_acc, h2);
  float rx, ry;
  if (end>beg){ rx = ax/sh; ry = ay/sh; } else { rx=0.f; ry=0.f; }
  rx += bias[c]; ry += bias[c+1];
  if (!FINAL){
    rx += resid[(size_t)node*D + c];
    ry += resid[(size_t)node*D + c+1];
    rx = fmaxf(rx,0.f); ry = fmaxf(ry,0.f);
  }
  *(float2*)&out[(size_t)node*D + c] = make_float2(rx,ry);
}

extern "C" void kernel_launch(void* const* d_in, const int* in_sizes, int n_in,
                              void* d_out, int out_size, void* d_ws, size_t ws_size,
                              hipStream_t stream){
  const float* in_feat = (const float*)d_in[0];
  const float* ew  = (const float*)d_in[1];
  const float* W0  = (const float*)d_in[2];
  const float* al0 = (const float*)d_in[3];
  const float* ar0 = (const float*)d_in[4];
  const float* b0  = (const float*)d_in[5];
  const float* W1  = (const float*)d_in[6];
  const float* al1 = (const float*)d_in[7];
  const float* ar1 = (const float*)d_in[8];
  const float* b1  = (const float*)d_in[9];
  const int* src = (const int*)d_in[10];
  const int* dst = (const int*)d_in[11];
  float* out = (float*)d_out;

  char* p = (char*)d_ws;
  auto alloc = [&](size_t b)->void*{ void* r=(void*)p; p += ((b+255)&~(size_t)255); return r; };
  int*   counts = (int*)alloc((size_t)NN*4);
  int*   offs   = (int*)alloc((size_t)(NN+1)*4);
  int*   cursor = (int*)alloc((size_t)NN*4);
  int*   partial= (int*)alloc(64*4);
  int*   src_s  = (int*)alloc((size_t)NE*4);
  float* w_s    = (float*)alloc((size_t)NE*4);
  float* bufA   = (float*)alloc((size_t)NN*D*4);
  float* bufB   = (float*)alloc((size_t)NN*D*4);
  float* bufC   = (float*)alloc((size_t)NN*D*4);
  float* el     = (float*)alloc((size_t)NN*NH*4);
  float* er     = (float*)alloc((size_t)NN*NH*4);

  hipMemsetAsync(counts, 0, (size_t)NN*4, stream);
  k_hist<<<(NE+255)/256, 256, 0, stream>>>(dst, counts);
  int nb = (NN+1023)/1024; // 49
  k_scan_a<<<nb,256,0,stream>>>(counts, partial);
  k_scan_b<<<1,64,0,stream>>>(partial, nb);
  k_scan_c<<<nb,256,0,stream>>>(counts, partial, offs, cursor);
  k_scatter<<<(NE+255)/256,256,0,stream>>>(src, dst, ew, cursor, src_s, w_s);

  int nwb = (NN*64 + 255)/256; // 12500 blocks, 4 waves (nodes) per block
  int ngb = (NN+127)/128;      // 391 GEMM blocks

  // layer 0
  k_wagg<<<nwb,256,0,stream>>>(in_feat, offs, src_s, w_s, bufA);
  k_gemm<<<ngb,256,0,stream>>>(bufA, W0, al0, ar0, bufB, (float4*)el, (float4*)er);
  k_gat<0><<<nwb,256,0,stream>>>(bufB, (float4*)el, (float4*)er, b0, offs, src_s, in_feat, bufC);

  // layer 1
  k_wagg<<<nwb,256,0,stream>>>(bufC, offs, src_s, w_s, bufA);
  k_gemm<<<ngb,256,0,stream>>>(bufA, W1, al1, ar1, bufB, (float4*)el, (float4*)er);
  k_gat<1><<<nwb,256,0,stream>>>(bufB, (float4*)el, (float4*)er, b1, offs, src_s, nullptr, out);
}

// Round 3
// 405.915 us; speedup vs baseline: 1.7419x; 1.1705x over previous
//
#include <hip/hip_runtime.h>

#define NN 50000
#define NE 800000
#define D 128
#define NH 4

typedef __attribute__((ext_vector_type(8))) short bf16x8;
typedef __attribute__((ext_vector_type(4))) float f32x4;

__device__ __forceinline__ float lrelu(float x){ return x > 0.f ? x : 0.2f*x; }
__device__ __forceinline__ float sel4(int h, float4 v){
  float r = v.x;
  r = (h==1)? v.y : r;
  r = (h==2)? v.z : r;
  r = (h==3)? v.w : r;
  return r;
}
__device__ __forceinline__ ushort f2bf(float f){
  union{ float f; uint i;} v; v.f=f;
  uint r = v.i + 0x7FFFu + ((v.i>>16)&1u);
  return (ushort)(r>>16);
}
__device__ __forceinline__ uint pack2bf(float x, float y){
  return (uint)f2bf(x) | ((uint)f2bf(y)<<16);
}
__device__ __forceinline__ float bflo(uint u){ return __uint_as_float(u<<16); }
__device__ __forceinline__ float bfhi(uint u){ return __uint_as_float(u & 0xffff0000u); }

// ---------- CSR build ----------

__global__ void k_hist(const int* __restrict__ dst, int* __restrict__ counts){
  int i = blockIdx.x*256 + threadIdx.x;
  if (i < NE) atomicAdd(&counts[dst[i]], 1);
}

__global__ void k_scan_a(const int* __restrict__ counts, int* __restrict__ partial){
  __shared__ int sd[256];
  int t = threadIdx.x;
  int base = blockIdx.x*1024 + t*4;
  int s = 0;
  #pragma unroll
  for (int k=0;k<4;k++){ int i = base+k; if (i<NN) s += counts[i]; }
  sd[t]=s; __syncthreads();
  for (int off=128; off>=1; off>>=1){
    if (t<off) sd[t]+=sd[t+off];
    __syncthreads();
  }
  if (t==0) partial[blockIdx.x]=sd[0];
}

__global__ void k_scan_b(int* __restrict__ partial, int nb){
  if (threadIdx.x==0 && blockIdx.x==0){
    int run=0;
    for (int i=0;i<nb;i++){ int v=partial[i]; partial[i]=run; run+=v; }
  }
}

__global__ void k_scan_c(const int* __restrict__ counts, const int* __restrict__ partial,
                         int* __restrict__ offs, int* __restrict__ cursor){
  __shared__ int sd[256];
  int t = threadIdx.x;
  int base = blockIdx.x*1024 + t*4;
  int c0=0,c1=0,c2=0,c3=0;
  if (base+0<NN) c0=counts[base+0];
  if (base+1<NN) c1=counts[base+1];
  if (base+2<NN) c2=counts[base+2];
  if (base+3<NN) c3=counts[base+3];
  int tot = c0+c1+c2+c3;
  sd[t]=tot; __syncthreads();
  for (int off=1; off<256; off<<=1){
    int add = (t>=off)? sd[t-off]:0;
    __syncthreads();
    sd[t]+=add;
    __syncthreads();
  }
  int excl = sd[t]-tot + partial[blockIdx.x];
  int o0=excl, o1=o0+c0, o2=o1+c1, o3=o2+c2;
  if (base+0<NN){ offs[base+0]=o0; cursor[base+0]=o0; }
  if (base+1<NN){ offs[base+1]=o1; cursor[base+1]=o1; }
  if (base+2<NN){ offs[base+2]=o2; cursor[base+2]=o2; }
  if (base+3<NN){ offs[base+3]=o3; cursor[base+3]=o3; }
  if (blockIdx.x==0 && t==0) offs[NN]=NE;
}

__global__ void k_scatter(const int* __restrict__ src, const int* __restrict__ dst,
                          const float* __restrict__ w, int* __restrict__ cursor,
                          int* __restrict__ src_s, float* __restrict__ w_s){
  int i = blockIdx.x*256 + threadIdx.x;
  if (i<NE){
    int d = dst[i];
    int pos = atomicAdd(&cursor[d],1);
    src_s[pos]=src[i];
    w_s[pos]=w[i];
  }
}

// ---------- conversions ----------

// f32 [N,128] -> packed bf16 rows (uint = 2 cols)
__global__ void k_cvt(const float* __restrict__ in, uint* __restrict__ out16, int n2){
  int i = blockIdx.x*256 + threadIdx.x;   // one uint (2 floats) per thread
  if (i < n2){
    float2 f = *(const float2*)&in[(size_t)i*2];
    out16[i] = pack2bf(f.x, f.y);
  }
}

// W f32 [k=128][n=128] -> Wt bf16 packed [n][k/2 uints]
__global__ void k_cvtW(const float* __restrict__ W, uint* __restrict__ Wt){
  int i = blockIdx.x*256 + threadIdx.x;   // i = n*64 + k2
  if (i < 128*64){
    int n = i>>6, k2 = i&63;
    float a = W[(size_t)(2*k2)*128 + n];
    float b = W[(size_t)(2*k2+1)*128 + n];
    Wt[i] = pack2bf(a,b);
  }
}

// ---------- weighted aggregation: x[v] = h[v] + sum_{e:dst=v} w_e * h[src_e]  (bf16 gather) ----------
__global__ void k_wagg(const float* __restrict__ hinF, const uint* __restrict__ hin16,
                       const int* __restrict__ offs,
                       const int* __restrict__ src_s, const float* __restrict__ w_s,
                       uint* __restrict__ xout16){
  int node = (blockIdx.x*256 + threadIdx.x)>>6;
  int lane = threadIdx.x & 63;
  if (node>=NN) return;
  int beg=offs[node], end=offs[node+1];
  float2 acc = *(const float2*)&hinF[(size_t)node*D + lane*2];
  for (int cb=beg; cb<end; cb+=64){
    int n = end-cb; if (n>64) n=64;
    int idx = cb + (lane<n ? lane : 0);
    int sp = src_s[idx];
    float wp = w_s[idx];
    for (int j=0;j<n;j++){
      int s = __shfl(sp, j);
      float w = __shfl(wp, j);
      uint u = hin16[(size_t)s*64 + lane];
      acc.x = fmaf(bflo(u), w, acc.x);
      acc.y = fmaf(bfhi(u), w, acc.y);
    }
  }
  xout16[(size_t)node*64 + lane] = pack2bf(acc.x, acc.y);
}

// ---------- MFMA GEMM: featF = X16 @ Wt16 (both bf16, f32 out), 128x128 tile ----------
__global__ __launch_bounds__(256) void k_gemm(const uint* __restrict__ X16, const uint* __restrict__ Wt16,
                                              float* __restrict__ feat){
  __shared__ uint sX[128*64];
  __shared__ uint sW[128*64];
  int t = threadIdx.x;
  int row0 = blockIdx.x*128;
  // stage X tile (swizzled: 16B chunk cb at row r goes to uint offset (cb*4)^((r&7)<<2))
  #pragma unroll
  for (int i=0;i<8;i++){
    int idx = t + 256*i;           // 0..2047 chunk id
    int r = idx>>4, cb = idx&15;
    int gr = row0 + r;
    uint4 v = make_uint4(0u,0u,0u,0u);
    if (gr < NN) v = *(const uint4*)&X16[(size_t)gr*64 + cb*4];
    *(uint4*)&sX[r*64 + ((cb*4) ^ ((r&7)<<2))] = v;
  }
  #pragma unroll
  for (int i=0;i<8;i++){
    int idx = t + 256*i;
    int r = idx>>4, cb = idx&15;
    uint4 v = *(const uint4*)&Wt16[(size_t)r*64 + cb*4];
    *(uint4*)&sW[r*64 + ((cb*4) ^ ((r&7)<<2))] = v;
  }
  __syncthreads();
  int w = t>>6, l = t&63;
  int lr = l&15, lk = l>>4;
  f32x4 acc[2][8];
  #pragma unroll
  for (int rf=0;rf<2;rf++)
    #pragma unroll
    for (int cf=0;cf<8;cf++) acc[rf][cf] = (f32x4){0.f,0.f,0.f,0.f};
  #pragma unroll
  for (int ks=0; ks<4; ks++){
    int cb = ks*4 + lk;
    bf16x8 a[2], b[8];
    #pragma unroll
    for (int rf=0;rf<2;rf++){
      int r = w*32 + rf*16 + lr;
      a[rf] = *(const bf16x8*)&sX[r*64 + ((cb*4) ^ ((r&7)<<2))];
    }
    #pragma unroll
    for (int cf=0;cf<8;cf++){
      int r = cf*16 + lr;
      b[cf] = *(const bf16x8*)&sW[r*64 + ((cb*4) ^ ((r&7)<<2))];
    }
    #pragma unroll
    for (int rf=0;rf<2;rf++)
      #pragma unroll
      for (int cf=0;cf<8;cf++)
        acc[rf][cf] = __builtin_amdgcn_mfma_f32_16x16x32_bf16(a[rf], b[cf], acc[rf][cf], 0,0,0);
  }
  // epilogue: D row = (lane>>4)*4+reg, col = lane&15
  #pragma unroll
  for (int rf=0;rf<2;rf++){
    #pragma unroll
    for (int cf=0;cf<8;cf++){
      int col = cf*16 + lr;
      #pragma unroll
      for (int reg=0;reg<4;reg++){
        int row = row0 + w*32 + rf*16 + lk*4 + reg;
        if (row < NN) feat[(size_t)row*D + col] = acc[rf][cf][reg];
      }
    }
  }
}

// ---------- el/er dot products + bf16 copy of feat ----------
__global__ void k_elr(const float* __restrict__ feat, const float* __restrict__ al,
                      const float* __restrict__ ar, float* __restrict__ el,
                      float* __restrict__ er, uint* __restrict__ feat16){
  int node = (blockIdx.x*256 + threadIdx.x)>>6;
  int lane = threadIdx.x & 63;
  if (node>=NN) return;
  float2 f = *(const float2*)&feat[(size_t)node*D + lane*2];
  feat16[(size_t)node*64 + lane] = pack2bf(f.x, f.y);
  float e = f.x*al[lane*2] + f.y*al[lane*2+1];
  float r = f.x*ar[lane*2] + f.y*ar[lane*2+1];
  #pragma unroll
  for (int off=8; off>=1; off>>=1){
    e += __shfl_xor(e, off);
    r += __shfl_xor(r, off);
  }
  if ((lane&15)==0){
    el[node*NH + (lane>>4)] = e;
    er[node*NH + (lane>>4)] = r;
  }
}

// ---------- GAT edge-softmax + aggregation (bf16 feat gather) ----------
template<int FINAL>
__global__ void k_gat(const uint* __restrict__ feat16, const float4* __restrict__ el4,
                      const float4* __restrict__ er4, const float* __restrict__ bias,
                      const int* __restrict__ offs, const int* __restrict__ src_s,
                      const float* __restrict__ resid, float* __restrict__ out,
                      uint* __restrict__ out16){
  int node = (blockIdx.x*256 + threadIdx.x)>>6;
  int lane = threadIdx.x & 63;
  if (node>=NN) return;
  int beg=offs[node], end=offs[node+1];
  int c = lane*2;
  int h2 = lane>>4;
  float4 erv = er4[node];
  // pass A: per-head max of el over srcs (lrelu monotone: m = lrelu(max el + er))
  float4 mx = make_float4(-3e38f,-3e38f,-3e38f,-3e38f);
  for (int j=beg+lane; j<end; j+=64){
    float4 v = el4[src_s[j]];
    mx.x=fmaxf(mx.x,v.x); mx.y=fmaxf(mx.y,v.y);
    mx.z=fmaxf(mx.z,v.z); mx.w=fmaxf(mx.w,v.w);
  }
  #pragma unroll
  for (int off=32; off>=1; off>>=1){
    mx.x=fmaxf(mx.x,__shfl_xor(mx.x,off));
    mx.y=fmaxf(mx.y,__shfl_xor(mx.y,off));
    mx.z=fmaxf(mx.z,__shfl_xor(mx.z,off));
    mx.w=fmaxf(mx.w,__shfl_xor(mx.w,off));
  }
  float4 m = make_float4(lrelu(mx.x+erv.x), lrelu(mx.y+erv.y),
                         lrelu(mx.z+erv.z), lrelu(mx.w+erv.w));
  int hp = lane & 3;
  float mh  = sel4(hp, m);
  float erh = sel4(hp, erv);
  int eidx = lane>>2;
  float s_acc = 0.f;
  float ax=0.f, ay=0.f;
  for (int cb=beg; cb<end; cb+=16){
    int n = end-cb; if (n>16) n=16;
    int j = cb + (eidx<n ? eidx : 0);
    int sp = src_s[j];
    float4 ev = el4[sp];
    float e = expf(lrelu(sel4(hp,ev) + erh) - mh);
    e = (eidx<n) ? e : 0.f;
    s_acc += e;
    for (int q=0;q<n;q++){
      int sl = q<<2;
      int sj = __shfl(sp, sl);
      float eh = __shfl(e, sl + h2);
      uint u = feat16[(size_t)sj*64 + lane];
      ax = fmaf(bflo(u), eh, ax);
      ay = fmaf(bfhi(u), eh, ay);
    }
  }
  s_acc += __shfl_xor(s_acc,4);
  s_acc += __shfl_xor(s_acc,8);
  s_acc += __shfl_xor(s_acc,16);
  s_acc += __shfl_xor(s_acc,32);
  float sh = __shfl(s_acc, h2);
  float rx, ry;
  if (end>beg){ rx = ax/sh; ry = ay/sh; } else { rx=0.f; ry=0.f; }
  rx += bias[c]; ry += bias[c+1];
  if (!FINAL){
    rx += resid[(size_t)node*D + c];
    ry += resid[(size_t)node*D + c+1];
    rx = fmaxf(rx,0.f); ry = fmaxf(ry,0.f);
    out16[(size_t)node*64 + lane] = pack2bf(rx,ry);
  }
  *(float2*)&out[(size_t)node*D + c] = make_float2(rx,ry);
}

extern "C" void kernel_launch(void* const* d_in, const int* in_sizes, int n_in,
                              void* d_out, int out_size, void* d_ws, size_t ws_size,
                              hipStream_t stream){
  const float* in_feat = (const float*)d_in[0];
  const float* ew  = (const float*)d_in[1];
  const float* W0  = (const float*)d_in[2];
  const float* al0 = (const float*)d_in[3];
  const float* ar0 = (const float*)d_in[4];
  const float* b0  = (const float*)d_in[5];
  const float* W1  = (const float*)d_in[6];
  const float* al1 = (const float*)d_in[7];
  const float* ar1 = (const float*)d_in[8];
  const float* b1  = (const float*)d_in[9];
  const int* src = (const int*)d_in[10];
  const int* dst = (const int*)d_in[11];
  float* out = (float*)d_out;

  char* p = (char*)d_ws;
  auto alloc = [&](size_t b)->void*{ void* r=(void*)p; p += ((b+255)&~(size_t)255); return r; };
  int*   counts = (int*)alloc((size_t)NN*4);
  int*   offs   = (int*)alloc((size_t)(NN+1)*4);
  int*   cursor = (int*)alloc((size_t)NN*4);
  int*   partial= (int*)alloc(64*4);
  int*   src_s  = (int*)alloc((size_t)NE*4);
  float* w_s    = (float*)alloc((size_t)NE*4);
  uint*  h16    = (uint*)alloc((size_t)NN*64*4);   // layer-0 in16, reused as bufC16 by k_gat<0>
  uint*  X16    = (uint*)alloc((size_t)NN*64*4);   // GEMM input
  float* featF  = (float*)alloc((size_t)NN*D*4);   // GEMM f32 out, reused as bufC by k_gat<0>
  uint*  feat16 = (uint*)alloc((size_t)NN*64*4);   // bf16 feat for gather
  uint*  Wt0    = (uint*)alloc((size_t)128*64*4);
  uint*  Wt1    = (uint*)alloc((size_t)128*64*4);
  float* el     = (float*)alloc((size_t)NN*NH*4);
  float* er     = (float*)alloc((size_t)NN*NH*4);
  float* bufC   = featF;   // alias: featF consumed by k_elr before k_gat<0> writes bufC
  uint*  bufC16 = h16;     // alias: h16 consumed by layer-0 wagg before k_gat<0> writes

  hipMemsetAsync(counts, 0, (size_t)NN*4, stream);
  k_hist<<<(NE+255)/256, 256, 0, stream>>>(dst, counts);
  int nb = (NN+1023)/1024; // 49
  k_scan_a<<<nb,256,0,stream>>>(counts, partial);
  k_scan_b<<<1,64,0,stream>>>(partial, nb);
  k_scan_c<<<nb,256,0,stream>>>(counts, partial, offs, cursor);
  k_scatter<<<(NE+255)/256,256,0,stream>>>(src, dst, ew, cursor, src_s, w_s);
  k_cvt<<<(NN*64+255)/256,256,0,stream>>>(in_feat, h16, NN*64);
  k_cvtW<<<(128*64+255)/256,256,0,stream>>>(W0, Wt0);
  k_cvtW<<<(128*64+255)/256,256,0,stream>>>(W1, Wt1);

  int nwb = (NN*64 + 255)/256; // 12500 blocks (4 waves = 4 nodes each)
  int ngb = (NN+127)/128;      // 391 GEMM blocks

  // layer 0
  k_wagg<<<nwb,256,0,stream>>>(in_feat, h16, offs, src_s, w_s, X16);
  k_gemm<<<ngb,256,0,stream>>>(X16, Wt0, featF);
  k_elr<<<nwb,256,0,stream>>>(featF, al0, ar0, el, er, feat16);
  k_gat<0><<<nwb,256,0,stream>>>(feat16, (const float4*)el, (const float4*)er, b0,
                                 offs, src_s, in_feat, bufC, bufC16);
  // layer 1
  k_wagg<<<nwb,256,0,stream>>>(bufC, bufC16, offs, src_s, w_s, X16);
  k_gemm<<<ngb,256,0,stream>>>(X16, Wt1, featF);
  k_elr<<<nwb,256,0,stream>>>(featF, al1, ar1, el, er, feat16);
  k_gat<1><<<nwb,256,0,stream>>>(feat16, (const float4*)el, (const float4*)er, b1,
                                 offs, src_s, nullptr, out, nullptr);
}

// Round 4
// 343.777 us; speedup vs baseline: 2.0567x; 1.1808x over previous
//
#include <hip/hip_runtime.h>

#define NN 50000
#define NE 800000
#define D 128
#define NH 4

typedef __attribute__((ext_vector_type(8))) short bf16x8;
typedef __attribute__((ext_vector_type(4))) float f32x4;

__device__ __forceinline__ float lrelu(float x){ return x > 0.f ? x : 0.2f*x; }
__device__ __forceinline__ float sel4(int h, float4 v){
  float r = v.x;
  r = (h==1)? v.y : r;
  r = (h==2)? v.z : r;
  r = (h==3)? v.w : r;
  return r;
}
__device__ __forceinline__ ushort f2bf(float f){
  union{ float f; uint i;} v; v.f=f;
  uint r = v.i + 0x7FFFu + ((v.i>>16)&1u);
  return (ushort)(r>>16);
}
__device__ __forceinline__ uint pack2bf(float x, float y){
  return (uint)f2bf(x) | ((uint)f2bf(y)<<16);
}
__device__ __forceinline__ float bflo(uint u){ return __uint_as_float(u<<16); }
__device__ __forceinline__ float bfhi(uint u){ return __uint_as_float(u & 0xffff0000u); }
// monotone float<->uint encoding for atomicMax on floats
__device__ __forceinline__ uint encf(float f){
  uint b = __float_as_uint(f);
  return (b & 0x80000000u) ? ~b : (b | 0x80000000u);
}
__device__ __forceinline__ float decf(uint e){
  return (e & 0x80000000u) ? __uint_as_float(e ^ 0x80000000u) : __uint_as_float(~e);
}

// ---------- CSR build ----------

__global__ void k_hist(const int* __restrict__ dst, int* __restrict__ counts){
  int i = blockIdx.x*256 + threadIdx.x;
  if (i < NE) atomicAdd(&counts[dst[i]], 1);
}

__global__ void k_scan_a(const int* __restrict__ counts, int* __restrict__ partial){
  __shared__ int sd[256];
  int t = threadIdx.x;
  int base = blockIdx.x*1024 + t*4;
  int s = 0;
  #pragma unroll
  for (int k=0;k<4;k++){ int i = base+k; if (i<NN) s += counts[i]; }
  sd[t]=s; __syncthreads();
  for (int off=128; off>=1; off>>=1){
    if (t<off) sd[t]+=sd[t+off];
    __syncthreads();
  }
  if (t==0) partial[blockIdx.x]=sd[0];
}

__global__ void k_scan_b(int* __restrict__ partial, int nb){
  if (threadIdx.x==0 && blockIdx.x==0){
    int run=0;
    for (int i=0;i<nb;i++){ int v=partial[i]; partial[i]=run; run+=v; }
  }
}

__global__ void k_scan_c(const int* __restrict__ counts, const int* __restrict__ partial,
                         int* __restrict__ offs, int* __restrict__ cursor){
  __shared__ int sd[256];
  int t = threadIdx.x;
  int base = blockIdx.x*1024 + t*4;
  int c0=0,c1=0,c2=0,c3=0;
  if (base+0<NN) c0=counts[base+0];
  if (base+1<NN) c1=counts[base+1];
  if (base+2<NN) c2=counts[base+2];
  if (base+3<NN) c3=counts[base+3];
  int tot = c0+c1+c2+c3;
  sd[t]=tot; __syncthreads();
  for (int off=1; off<256; off<<=1){
    int add = (t>=off)? sd[t-off]:0;
    __syncthreads();
    sd[t]+=add;
    __syncthreads();
  }
  int excl = sd[t]-tot + partial[blockIdx.x];
  int o0=excl, o1=o0+c0, o2=o1+c1, o3=o2+c2;
  if (base+0<NN){ offs[base+0]=o0; cursor[base+0]=o0; }
  if (base+1<NN){ offs[base+1]=o1; cursor[base+1]=o1; }
  if (base+2<NN){ offs[base+2]=o2; cursor[base+2]=o2; }
  if (base+3<NN){ offs[base+3]=o3; cursor[base+3]=o3; }
  if (blockIdx.x==0 && t==0) offs[NN]=NE;
}

__global__ void k_scatter(const int* __restrict__ src, const int* __restrict__ dst,
                          const float* __restrict__ w, int* __restrict__ cursor,
                          int* __restrict__ src_s, float* __restrict__ w_s){
  int i = blockIdx.x*256 + threadIdx.x;
  if (i<NE){
    int d = dst[i];
    int pos = atomicAdd(&cursor[d],1);
    src_s[pos]=src[i];
    w_s[pos]=w[i];
  }
}

// ---------- conversions ----------

__global__ void k_cvt(const float* __restrict__ in, uint* __restrict__ out16, int n2){
  int i = blockIdx.x*256 + threadIdx.x;
  if (i < n2){
    float2 f = *(const float2*)&in[(size_t)i*2];
    out16[i] = pack2bf(f.x, f.y);
  }
}

// W f32 [k=128][n=128] -> Wt bf16 packed [n][k/2 uints]
__global__ void k_cvtW(const float* __restrict__ W, uint* __restrict__ Wt){
  int i = blockIdx.x*256 + threadIdx.x;
  if (i < 128*64){
    int n = i>>6, k2 = i&63;
    float a = W[(size_t)(2*k2)*128 + n];
    float b = W[(size_t)(2*k2+1)*128 + n];
    Wt[i] = pack2bf(a,b);
  }
}

// ---------- weighted aggregation: x[v] = h[v] + sum w_e * h[src_e]  (bf16 gather, batched) ----------
// one wave per node; half-wave per edge; lane covers 4 cols (uint2)
__global__ void k_wagg(const float* __restrict__ hinF, const uint* __restrict__ hin16,
                       const int* __restrict__ offs,
                       const int* __restrict__ src_s, const float* __restrict__ w_s,
                       uint* __restrict__ xout16){
  int node = (blockIdx.x*256 + threadIdx.x)>>6;
  int lane = threadIdx.x & 63;
  if (node>=NN) return;
  int beg=offs[node], end=offs[node+1];
  int half = lane>>5, li = lane&31;
  float a0=0.f,a1=0.f,a2=0.f,a3=0.f;
  if (half==0){
    float4 s4 = *(const float4*)&hinF[(size_t)node*D + li*4];
    a0=s4.x; a1=s4.y; a2=s4.z; a3=s4.w;
  }
  for (int cb=beg; cb<end; cb+=64){
    int n = end-cb; if (n>64) n=64;
    int idx = cb + (lane<n ? lane : n-1);
    int sp = src_s[idx];
    float wp = w_s[idx];
    int iters = (n+1)>>1;
    for (int i0=0; i0<iters; i0+=8){
      uint2 u[8]; float wk[8];
      #pragma unroll
      for (int k=0;k<8;k++){
        int q = 2*(i0+k) + half;
        int sj = __shfl(sp, q & 63);
        float wq = __shfl(wp, q & 63);
        wk[k] = (q<n)? wq : 0.f;
        u[k] = *(const uint2*)&hin16[(size_t)sj*64 + li*2];
      }
      #pragma unroll
      for (int k=0;k<8;k++){
        a0 = fmaf(bflo(u[k].x), wk[k], a0);
        a1 = fmaf(bfhi(u[k].x), wk[k], a1);
        a2 = fmaf(bflo(u[k].y), wk[k], a2);
        a3 = fmaf(bfhi(u[k].y), wk[k], a3);
      }
    }
  }
  a0 += __shfl_xor(a0,32); a1 += __shfl_xor(a1,32);
  a2 += __shfl_xor(a2,32); a3 += __shfl_xor(a3,32);
  if (half==0){
    uint2 o; o.x = pack2bf(a0,a1); o.y = pack2bf(a2,a3);
    *(uint2*)&xout16[(size_t)node*64 + li*2] = o;
  }
}

// ---------- MFMA GEMM (bf16 in, f32 acc) + fused epilogue: feat16 bf16 + el/er ----------
__global__ __launch_bounds__(256) void k_gemm(const uint* __restrict__ X16, const uint* __restrict__ Wt16,
    const float* __restrict__ al, const float* __restrict__ ar,
    uint* __restrict__ feat16, float4* __restrict__ el4o, float4* __restrict__ er4o){
  __shared__ uint sX[128*64];
  __shared__ uint sW[128*64];
  int t = threadIdx.x;
  int row0 = blockIdx.x*128;
  #pragma unroll
  for (int i=0;i<8;i++){
    int idx = t + 256*i;
    int r = idx>>4, cb = idx&15;
    int gr = row0 + r;
    uint4 v = make_uint4(0u,0u,0u,0u);
    if (gr < NN) v = *(const uint4*)&X16[(size_t)gr*64 + cb*4];
    *(uint4*)&sX[r*64 + ((cb*4) ^ ((r&7)<<2))] = v;
  }
  #pragma unroll
  for (int i=0;i<8;i++){
    int idx = t + 256*i;
    int r = idx>>4, cb = idx&15;
    uint4 v = *(const uint4*)&Wt16[(size_t)r*64 + cb*4];
    *(uint4*)&sW[r*64 + ((cb*4) ^ ((r&7)<<2))] = v;
  }
  __syncthreads();
  int w = t>>6, l = t&63;
  int lr = l&15, lk = l>>4;
  f32x4 acc[2][8];
  #pragma unroll
  for (int rf=0;rf<2;rf++)
    #pragma unroll
    for (int cf=0;cf<8;cf++) acc[rf][cf] = (f32x4){0.f,0.f,0.f,0.f};
  #pragma unroll
  for (int ks=0; ks<4; ks++){
    int cb = ks*4 + lk;
    bf16x8 a[2], b[8];
    #pragma unroll
    for (int rf=0;rf<2;rf++){
      int r = w*32 + rf*16 + lr;
      a[rf] = *(const bf16x8*)&sX[r*64 + ((cb*4) ^ ((r&7)<<2))];
    }
    #pragma unroll
    for (int cf=0;cf<8;cf++){
      int r = cf*16 + lr;
      b[cf] = *(const bf16x8*)&sW[r*64 + ((cb*4) ^ ((r&7)<<2))];
    }
    #pragma unroll
    for (int rf=0;rf<2;rf++)
      #pragma unroll
      for (int cf=0;cf<8;cf++)
        acc[rf][cf] = __builtin_amdgcn_mfma_f32_16x16x32_bf16(a[rf], b[cf], acc[rf][cf], 0,0,0);
  }
  // epilogue
  float al_v[8], ar_v[8];
  #pragma unroll
  for (int cf=0;cf<8;cf++){ al_v[cf]=al[cf*16+lr]; ar_v[cf]=ar[cf*16+lr]; }
  #pragma unroll
  for (int rf=0;rf<2;rf++){
    #pragma unroll
    for (int reg=0;reg<4;reg++){
      int grow = row0 + w*32 + rf*16 + lk*4 + reg;
      float eh[4]={0.f,0.f,0.f,0.f}, fh[4]={0.f,0.f,0.f,0.f};
      #pragma unroll
      for (int cf=0;cf<8;cf++){
        float v = acc[rf][cf][reg];
        eh[cf>>1] = fmaf(v, al_v[cf], eh[cf>>1]);
        fh[cf>>1] = fmaf(v, ar_v[cf], fh[cf>>1]);
      }
      #pragma unroll
      for (int off=1; off<16; off<<=1){
        #pragma unroll
        for (int h=0;h<4;h++){
          eh[h] += __shfl_xor(eh[h], off);
          fh[h] += __shfl_xor(fh[h], off);
        }
      }
      if (lr==0 && grow<NN){
        el4o[grow] = make_float4(eh[0],eh[1],eh[2],eh[3]);
        er4o[grow] = make_float4(fh[0],fh[1],fh[2],fh[3]);
      }
      #pragma unroll
      for (int cf=0;cf<8;cf++){
        float v = acc[rf][cf][reg];
        float pv = __shfl_xor(v, 1);
        if (!(lr&1) && grow<NN)
          feat16[(size_t)grow*64 + ((cf*16+lr)>>1)] = pack2bf(v, pv);
      }
    }
  }
}

// ---------- global per-head max of el ----------
__global__ void k_gmax(const float4* __restrict__ el4, uint* __restrict__ gmax_u){
  int tid = blockIdx.x*256 + threadIdx.x;
  float m0=-3e38f,m1=-3e38f,m2=-3e38f,m3=-3e38f;
  for (int i=tid; i<NN; i += gridDim.x*256){
    float4 v = el4[i];
    m0=fmaxf(m0,v.x); m1=fmaxf(m1,v.y); m2=fmaxf(m2,v.z); m3=fmaxf(m3,v.w);
  }
  #pragma unroll
  for (int off=32; off>=1; off>>=1){
    m0=fmaxf(m0,__shfl_xor(m0,off));
    m1=fmaxf(m1,__shfl_xor(m1,off));
    m2=fmaxf(m2,__shfl_xor(m2,off));
    m3=fmaxf(m3,__shfl_xor(m3,off));
  }
  if ((threadIdx.x&63)==0){
    atomicMax(&gmax_u[0], encf(m0));
    atomicMax(&gmax_u[1], encf(m1));
    atomicMax(&gmax_u[2], encf(m2));
    atomicMax(&gmax_u[3], encf(m3));
  }
}

// ---------- GAT edge-softmax + aggregation (single pass, batched gather) ----------
template<int FINAL>
__global__ void k_gat(const uint* __restrict__ feat16, const float4* __restrict__ el4,
                      const float4* __restrict__ er4, const uint* __restrict__ gmax_u,
                      const float* __restrict__ bias,
                      const int* __restrict__ offs, const int* __restrict__ src_s,
                      const float* __restrict__ resid, float* __restrict__ out,
                      uint* __restrict__ out16){
  int node = (blockIdx.x*256 + threadIdx.x)>>6;
  int lane = threadIdx.x & 63;
  if (node>=NN) return;
  int beg=offs[node], end=offs[node+1];
  int half = lane>>5, li = lane&31;
  int hF = li>>3;           // head of this lane's 4 columns
  int hp = lane & 3;        // head this lane's exp covers
  float4 erv = er4[node];
  uint4 g = *(const uint4*)gmax_u;
  float4 m4 = make_float4(lrelu(decf(g.x)+erv.x), lrelu(decf(g.y)+erv.y),
                          lrelu(decf(g.z)+erv.z), lrelu(decf(g.w)+erv.w));
  float mh  = sel4(hp, m4);
  float erh = sel4(hp, erv);
  float s_acc = 0.f;
  float a0=0.f,a1=0.f,a2=0.f,a3=0.f;
  int eidx = lane>>2;
  for (int cb=beg; cb<end; cb+=16){
    int n = end-cb; if (n>16) n=16;
    int j = cb + (eidx<n ? eidx : n-1);
    int sp = src_s[j];
    float4 ev = el4[sp];
    float e = __expf(lrelu(sel4(hp,ev)+erh) - mh);
    e = (eidx<n)? e : 0.f;
    s_acc += e;
    uint2 u[8]; float eh[8];
    #pragma unroll
    for (int k=0;k<8;k++){
      int bidx = (2*k + half)<<2;          // 0..60
      int sj = __shfl(sp, bidx);
      eh[k] = __shfl(e, bidx + hF);
      u[k] = *(const uint2*)&feat16[(size_t)sj*64 + li*2];
    }
    #pragma unroll
    for (int k=0;k<8;k++){
      a0 = fmaf(bflo(u[k].x), eh[k], a0);
      a1 = fmaf(bfhi(u[k].x), eh[k], a1);
      a2 = fmaf(bflo(u[k].y), eh[k], a2);
      a3 = fmaf(bfhi(u[k].y), eh[k], a3);
    }
  }
  // per-head denominator
  s_acc += __shfl_xor(s_acc,4);
  s_acc += __shfl_xor(s_acc,8);
  s_acc += __shfl_xor(s_acc,16);
  s_acc += __shfl_xor(s_acc,32);
  float sh = __shfl(s_acc, hF);
  // combine halves (even/odd edges)
  a0 += __shfl_xor(a0,32); a1 += __shfl_xor(a1,32);
  a2 += __shfl_xor(a2,32); a3 += __shfl_xor(a3,32);
  if (half==0){
    float inv = (end>beg)? 1.f/sh : 0.f;
    float4 bv = *(const float4*)&bias[li*4];
    float r0 = a0*inv + bv.x;
    float r1 = a1*inv + bv.y;
    float r2 = a2*inv + bv.z;
    float r3 = a3*inv + bv.w;
    if (!FINAL){
      float4 rs = *(const float4*)&resid[(size_t)node*D + li*4];
      r0 = fmaxf(r0+rs.x, 0.f);
      r1 = fmaxf(r1+rs.y, 0.f);
      r2 = fmaxf(r2+rs.z, 0.f);
      r3 = fmaxf(r3+rs.w, 0.f);
      uint2 o16; o16.x = pack2bf(r0,r1); o16.y = pack2bf(r2,r3);
      *(uint2*)&out16[(size_t)node*64 + li*2] = o16;
    }
    *(float4*)&out[(size_t)node*D + li*4] = make_float4(r0,r1,r2,r3);
  }
}

extern "C" void kernel_launch(void* const* d_in, const int* in_sizes, int n_in,
                              void* d_out, int out_size, void* d_ws, size_t ws_size,
                              hipStream_t stream){
  const float* in_feat = (const float*)d_in[0];
  const float* ew  = (const float*)d_in[1];
  const float* W0  = (const float*)d_in[2];
  const float* al0 = (const float*)d_in[3];
  const float* ar0 = (const float*)d_in[4];
  const float* b0  = (const float*)d_in[5];
  const float* W1  = (const float*)d_in[6];
  const float* al1 = (const float*)d_in[7];
  const float* ar1 = (const float*)d_in[8];
  const float* b1  = (const float*)d_in[9];
  const int* src = (const int*)d_in[10];
  const int* dst = (const int*)d_in[11];
  float* out = (float*)d_out;

  char* p = (char*)d_ws;
  auto alloc = [&](size_t b)->void*{ void* r=(void*)p; p += ((b+255)&~(size_t)255); return r; };
  int*   counts = (int*)alloc((size_t)NN*4);
  int*   offs   = (int*)alloc((size_t)(NN+1)*4);
  int*   cursor = (int*)alloc((size_t)NN*4);
  int*   partial= (int*)alloc(64*4);
  int*   src_s  = (int*)alloc((size_t)NE*4);
  float* w_s    = (float*)alloc((size_t)NE*4);
  uint*  h16    = (uint*)alloc((size_t)NN*64*4);   // layer-0 in16, reused as bufC16
  uint*  X16    = (uint*)alloc((size_t)NN*64*4);   // GEMM input
  uint*  feat16 = (uint*)alloc((size_t)NN*64*4);   // bf16 feat for gather
  float* bufC   = (float*)alloc((size_t)NN*D*4);   // layer-0 output (f32 resid path)
  uint*  Wt0    = (uint*)alloc((size_t)128*64*4);
  uint*  Wt1    = (uint*)alloc((size_t)128*64*4);
  float* el     = (float*)alloc((size_t)NN*NH*4);
  float* er     = (float*)alloc((size_t)NN*NH*4);
  uint*  gmax0  = (uint*)alloc(16);
  uint*  gmax1  = (uint*)alloc(16);
  uint*  bufC16 = h16;

  hipMemsetAsync(counts, 0, (size_t)NN*4, stream);
  hipMemsetAsync(gmax0, 0, 16, stream);
  hipMemsetAsync(gmax1, 0, 16, stream);
  k_hist<<<(NE+255)/256, 256, 0, stream>>>(dst, counts);
  int nb = (NN+1023)/1024; // 49
  k_scan_a<<<nb,256,0,stream>>>(counts, partial);
  k_scan_b<<<1,64,0,stream>>>(partial, nb);
  k_scan_c<<<nb,256,0,stream>>>(counts, partial, offs, cursor);
  k_scatter<<<(NE+255)/256,256,0,stream>>>(src, dst, ew, cursor, src_s, w_s);
  k_cvt<<<(NN*64+255)/256,256,0,stream>>>(in_feat, h16, NN*64);
  k_cvtW<<<(128*64+255)/256,256,0,stream>>>(W0, Wt0);
  k_cvtW<<<(128*64+255)/256,256,0,stream>>>(W1, Wt1);

  int nwb = (NN*64 + 255)/256; // 12500 blocks (4 waves = 4 nodes each)
  int ngb = (NN+127)/128;      // 391 GEMM blocks

  // layer 0
  k_wagg<<<nwb,256,0,stream>>>(in_feat, h16, offs, src_s, w_s, X16);
  k_gemm<<<ngb,256,0,stream>>>(X16, Wt0, al0, ar0, feat16, (float4*)el, (float4*)er);
  k_gmax<<<128,256,0,stream>>>((const float4*)el, gmax0);
  k_gat<0><<<nwb,256,0,stream>>>(feat16, (const float4*)el, (const float4*)er, gmax0, b0,
                                 offs, src_s, in_feat, bufC, bufC16);
  // layer 1
  k_wagg<<<nwb,256,0,stream>>>(bufC, bufC16, offs, src_s, w_s, X16);
  k_gemm<<<ngb,256,0,stream>>>(X16, Wt1, al1, ar1, feat16, (float4*)el, (float4*)er);
  k_gmax<<<128,256,0,stream>>>((const float4*)el, gmax1);
  k_gat<1><<<nwb,256,0,stream>>>(feat16, (const float4*)el, (const float4*)er, gmax1, b1,
                                 offs, src_s, nullptr, out, nullptr);
}

// Round 5
// 304.126 us; speedup vs baseline: 2.3249x; 1.1304x over previous
//
#include <hip/hip_runtime.h>

#define NN 50000
#define NE 800000
#define D 128
#define NH 4
#define NB 391   // (NN+127)/128 buckets of 128 nodes

typedef __attribute__((ext_vector_type(8))) short bf16x8;
typedef __attribute__((ext_vector_type(4))) float f32x4;

__device__ __forceinline__ float lrelu(float x){ return x > 0.f ? x : 0.2f*x; }
__device__ __forceinline__ ushort f2bf(float f){
  union{ float f; uint i;} v; v.f=f;
  uint r = v.i + 0x7FFFu + ((v.i>>16)&1u);
  return (ushort)(r>>16);
}
__device__ __forceinline__ uint pack2bf(float x, float y){
  return (uint)f2bf(x) | ((uint)f2bf(y)<<16);
}
__device__ __forceinline__ float bflo(uint u){ return __uint_as_float(u<<16); }
__device__ __forceinline__ float bfhi(uint u){ return __uint_as_float(u & 0xffff0000u); }
__device__ __forceinline__ uint encf(float f){
  uint b = __float_as_uint(f);
  return (b & 0x80000000u) ? ~b : (b | 0x80000000u);
}
__device__ __forceinline__ float decf(uint e){
  return (e & 0x80000000u) ? __uint_as_float(e ^ 0x80000000u) : __uint_as_float(~e);
}

// ---------- CSR build: bucket histogram -> scan -> binned scatter -> bucket finalize ----------

__global__ void k_bhist(const int* __restrict__ dst, int* __restrict__ bcnt){
  __shared__ int c[NB];
  int t = threadIdx.x;
  for (int i=t;i<NB;i+=256) c[i]=0;
  __syncthreads();
  int base = blockIdx.x*4096;
  #pragma unroll
  for (int k=0;k<16;k++){
    int i = base + k*256 + t;
    if (i<NE) atomicAdd(&c[dst[i]>>7], 1);
  }
  __syncthreads();
  for (int i=t;i<NB;i+=256){ int v=c[i]; if (v) atomicAdd(&bcnt[i], v); }
}

__global__ void k_bscan(const int* __restrict__ bcnt, int* __restrict__ boff, int* __restrict__ bcur){
  __shared__ int sd[512];
  int t = threadIdx.x;
  int own = (t<NB)? bcnt[t] : 0;
  sd[t] = own;
  __syncthreads();
  for (int off=1; off<512; off<<=1){
    int v = (t>=off)? sd[t-off] : 0;
    __syncthreads();
    sd[t] += v;
    __syncthreads();
  }
  if (t<NB){
    int excl = sd[t]-own;
    boff[t]=excl; bcur[t]=excl;
  }
  if (t==0) boff[NB]=NE;
}

// bin edges into bucket-contiguous staging (coalesced-ish writes), payload packed uint2
__global__ void k_binscat(const int* __restrict__ src, const int* __restrict__ dst,
                          const float* __restrict__ w, int* __restrict__ bcur,
                          uint2* __restrict__ stg){
  __shared__ int cnt[NB];
  __shared__ int st[NB];
  int t = threadIdx.x;
  for (int i=t;i<NB;i+=256) cnt[i]=0;
  __syncthreads();
  int base = blockIdx.x*4096;
  #pragma unroll
  for (int k=0;k<16;k++){
    int i = base + k*256 + t;
    if (i<NE) atomicAdd(&cnt[dst[i]>>7], 1);
  }
  __syncthreads();
  for (int i=t;i<NB;i+=256){
    int c = cnt[i];
    st[i] = c ? atomicAdd(&bcur[i], c) : 0;
    cnt[i] = 0;
  }
  __syncthreads();
  #pragma unroll
  for (int k=0;k<16;k++){
    int i = base + k*256 + t;
    if (i<NE){
      int d = dst[i];
      int b = d>>7;
      int pos = st[b] + atomicAdd(&cnt[b], 1);
      stg[pos] = make_uint2((uint)src[i] | ((uint)d<<16), __float_as_uint(w[i]));
    }
  }
}

// one block per bucket: per-node counts/scan in LDS, exact CSR positions, write offs + final edges
__global__ void k_bfinal(const uint2* __restrict__ stg, const int* __restrict__ boff,
                         int* __restrict__ offs, uint2* __restrict__ edge_s){
  int b = blockIdx.x, t = threadIdx.x;
  int beg = boff[b], end = boff[b+1];
  int node0 = b<<7;
  int nnode = NN - node0; if (nnode>128) nnode=128;
  __shared__ int cnt[128];
  __shared__ int cur[128];
  if (t<128) cnt[t]=0;
  __syncthreads();
  for (int j=beg+t; j<end; j+=256)
    atomicAdd(&cnt[(stg[j].x>>16)&127], 1);
  __syncthreads();
  int own = (t<128)? cnt[t] : 0;
  for (int off=1; off<128; off<<=1){
    int v = (t<128 && t>=off)? cnt[t-off] : 0;
    __syncthreads();
    if (t<128) cnt[t] += v;
    __syncthreads();
  }
  if (t<128){
    int excl = cnt[t]-own;
    cur[t] = beg + excl;
    if (t<nnode) offs[node0+t] = beg + excl;
  }
  if (b==NB-1 && t==0) offs[NN]=NE;
  __syncthreads();
  for (int j=beg+t; j<end; j+=256){
    uint2 v = stg[j];
    int pos = atomicAdd(&cur[(v.x>>16)&127], 1);
    edge_s[pos] = v;
  }
}

// ---------- conversions ----------

__global__ void k_cvt(const float* __restrict__ in, uint* __restrict__ out16, int n2){
  int i = blockIdx.x*256 + threadIdx.x;
  if (i < n2){
    float2 f = *(const float2*)&in[(size_t)i*2];
    out16[i] = pack2bf(f.x, f.y);
  }
}

__global__ void k_cvtW(const float* __restrict__ W, uint* __restrict__ Wt){
  int i = blockIdx.x*256 + threadIdx.x;
  if (i < 128*64){
    int n = i>>6, k2 = i&63;
    float a = W[(size_t)(2*k2)*128 + n];
    float b = W[(size_t)(2*k2+1)*128 + n];
    Wt[i] = pack2bf(a,b);
  }
}

// ---------- weighted aggregation (bf16 gather, batched, packed edges) ----------
__global__ void k_wagg(const float* __restrict__ hinF, const uint* __restrict__ hin16,
                       const int* __restrict__ offs, const uint2* __restrict__ edge_s,
                       uint* __restrict__ xout16){
  int node = (blockIdx.x*256 + threadIdx.x)>>6;
  int lane = threadIdx.x & 63;
  if (node>=NN) return;
  int beg=offs[node], end=offs[node+1];
  int half = lane>>5, li = lane&31;
  float a0=0.f,a1=0.f,a2=0.f,a3=0.f;
  if (half==0){
    float4 s4 = *(const float4*)&hinF[(size_t)node*D + li*4];
    a0=s4.x; a1=s4.y; a2=s4.z; a3=s4.w;
  }
  for (int cb=beg; cb<end; cb+=64){
    int n = end-cb; if (n>64) n=64;
    int idx = cb + (lane<n ? lane : n-1);
    uint2 ed = edge_s[idx];
    int sp = (int)(ed.x & 0xffffu);
    float wp = __uint_as_float(ed.y);
    int iters = (n+1)>>1;
    for (int i0=0; i0<iters; i0+=8){
      uint2 u[8]; float wk[8];
      #pragma unroll
      for (int k=0;k<8;k++){
        int q = 2*(i0+k) + half;
        int sj = __shfl(sp, q & 63);
        float wq = __shfl(wp, q & 63);
        wk[k] = (q<n)? wq : 0.f;
        u[k] = *(const uint2*)&hin16[(size_t)sj*64 + li*2];
      }
      #pragma unroll
      for (int k=0;k<8;k++){
        a0 = fmaf(bflo(u[k].x), wk[k], a0);
        a1 = fmaf(bfhi(u[k].x), wk[k], a1);
        a2 = fmaf(bflo(u[k].y), wk[k], a2);
        a3 = fmaf(bfhi(u[k].y), wk[k], a3);
      }
    }
  }
  a0 += __shfl_xor(a0,32); a1 += __shfl_xor(a1,32);
  a2 += __shfl_xor(a2,32); a3 += __shfl_xor(a3,32);
  if (half==0){
    uint2 o; o.x = pack2bf(a0,a1); o.y = pack2bf(a2,a3);
    *(uint2*)&xout16[(size_t)node*64 + li*2] = o;
  }
}

// ---------- MFMA GEMM (bf16 in, f32 acc) + fused epilogue: feat16 bf16 + el/er ----------
__global__ __launch_bounds__(256) void k_gemm(const uint* __restrict__ X16, const uint* __restrict__ Wt16,
    const float* __restrict__ al, const float* __restrict__ ar,
    uint* __restrict__ feat16, float4* __restrict__ el4o, float4* __restrict__ er4o){
  __shared__ uint sX[128*64];
  __shared__ uint sW[128*64];
  int t = threadIdx.x;
  int row0 = blockIdx.x*128;
  #pragma unroll
  for (int i=0;i<8;i++){
    int idx = t + 256*i;
    int r = idx>>4, cb = idx&15;
    int gr = row0 + r;
    uint4 v = make_uint4(0u,0u,0u,0u);
    if (gr < NN) v = *(const uint4*)&X16[(size_t)gr*64 + cb*4];
    *(uint4*)&sX[r*64 + ((cb*4) ^ ((r&7)<<2))] = v;
  }
  #pragma unroll
  for (int i=0;i<8;i++){
    int idx = t + 256*i;
    int r = idx>>4, cb = idx&15;
    uint4 v = *(const uint4*)&Wt16[(size_t)r*64 + cb*4];
    *(uint4*)&sW[r*64 + ((cb*4) ^ ((r&7)<<2))] = v;
  }
  __syncthreads();
  int w = t>>6, l = t&63;
  int lr = l&15, lk = l>>4;
  f32x4 acc[2][8];
  #pragma unroll
  for (int rf=0;rf<2;rf++)
    #pragma unroll
    for (int cf=0;cf<8;cf++) acc[rf][cf] = (f32x4){0.f,0.f,0.f,0.f};
  #pragma unroll
  for (int ks=0; ks<4; ks++){
    int cb = ks*4 + lk;
    bf16x8 a[2], b[8];
    #pragma unroll
    for (int rf=0;rf<2;rf++){
      int r = w*32 + rf*16 + lr;
      a[rf] = *(const bf16x8*)&sX[r*64 + ((cb*4) ^ ((r&7)<<2))];
    }
    #pragma unroll
    for (int cf=0;cf<8;cf++){
      int r = cf*16 + lr;
      b[cf] = *(const bf16x8*)&sW[r*64 + ((cb*4) ^ ((r&7)<<2))];
    }
    #pragma unroll
    for (int rf=0;rf<2;rf++)
      #pragma unroll
      for (int cf=0;cf<8;cf++)
        acc[rf][cf] = __builtin_amdgcn_mfma_f32_16x16x32_bf16(a[rf], b[cf], acc[rf][cf], 0,0,0);
  }
  float al_v[8], ar_v[8];
  #pragma unroll
  for (int cf=0;cf<8;cf++){ al_v[cf]=al[cf*16+lr]; ar_v[cf]=ar[cf*16+lr]; }
  #pragma unroll
  for (int rf=0;rf<2;rf++){
    #pragma unroll
    for (int reg=0;reg<4;reg++){
      int grow = row0 + w*32 + rf*16 + lk*4 + reg;
      float eh[4]={0.f,0.f,0.f,0.f}, fh[4]={0.f,0.f,0.f,0.f};
      #pragma unroll
      for (int cf=0;cf<8;cf++){
        float v = acc[rf][cf][reg];
        eh[cf>>1] = fmaf(v, al_v[cf], eh[cf>>1]);
        fh[cf>>1] = fmaf(v, ar_v[cf], fh[cf>>1]);
      }
      #pragma unroll
      for (int off=1; off<16; off<<=1){
        #pragma unroll
        for (int h=0;h<4;h++){
          eh[h] += __shfl_xor(eh[h], off);
          fh[h] += __shfl_xor(fh[h], off);
        }
      }
      if (lr==0 && grow<NN){
        el4o[grow] = make_float4(eh[0],eh[1],eh[2],eh[3]);
        er4o[grow] = make_float4(fh[0],fh[1],fh[2],fh[3]);
      }
      #pragma unroll
      for (int cf=0;cf<8;cf++){
        float v = acc[rf][cf][reg];
        float pv = __shfl_xor(v, 1);
        if (!(lr&1) && grow<NN)
          feat16[(size_t)grow*64 + ((cf*16+lr)>>1)] = pack2bf(v, pv);
      }
    }
  }
}

// ---------- global per-head max of el ----------
__global__ void k_gmax(const float4* __restrict__ el4, uint* __restrict__ gmax_u){
  int tid = blockIdx.x*256 + threadIdx.x;
  float m0=-3e38f,m1=-3e38f,m2=-3e38f,m3=-3e38f;
  for (int i=tid; i<NN; i += gridDim.x*256){
    float4 v = el4[i];
    m0=fmaxf(m0,v.x); m1=fmaxf(m1,v.y); m2=fmaxf(m2,v.z); m3=fmaxf(m3,v.w);
  }
  #pragma unroll
  for (int off=32; off>=1; off>>=1){
    m0=fmaxf(m0,__shfl_xor(m0,off));
    m1=fmaxf(m1,__shfl_xor(m1,off));
    m2=fmaxf(m2,__shfl_xor(m2,off));
    m3=fmaxf(m3,__shfl_xor(m3,off));
  }
  if ((threadIdx.x&63)==0){
    atomicMax(&gmax_u[0], encf(m0));
    atomicMax(&gmax_u[1], encf(m1));
    atomicMax(&gmax_u[2], encf(m2));
    atomicMax(&gmax_u[3], encf(m3));
  }
}

// ---------- edge-parallel exp: ee[e*4+h] ----------
__global__ void k_edge(const uint2* __restrict__ edge_s, const float* __restrict__ el,
                       const float* __restrict__ er, const uint* __restrict__ gmax_u,
                       float* __restrict__ ee){
  int id = blockIdx.x*256 + threadIdx.x;
  if (id >= NE*4) return;
  int e = id>>2, h = id&3;
  uint2 ed = edge_s[e];
  int s = (int)(ed.x & 0xffffu);
  int d = (int)(ed.x >> 16);
  float elv = el[s*4+h];
  float erv = er[d*4+h];
  float m = lrelu(decf(gmax_u[h]) + erv);
  ee[id] = __expf(lrelu(elv+erv) - m);
}

// ---------- GAT softmax-agg (bf16 gather, precomputed exp, coalesced ee loads) ----------
template<int FINAL>
__global__ void k_gat(const uint* __restrict__ feat16, const float* __restrict__ ee,
                      const uint2* __restrict__ edge_s, const float* __restrict__ bias,
                      const int* __restrict__ offs,
                      const float* __restrict__ resid, float* __restrict__ out,
                      uint* __restrict__ out16){
  int node = (blockIdx.x*256 + threadIdx.x)>>6;
  int lane = threadIdx.x & 63;
  if (node>=NN) return;
  int beg=offs[node], end=offs[node+1];
  int half = lane>>5, li = lane&31;
  int hF = li>>3;
  int eidx = lane>>2;
  float s_acc = 0.f;
  float a0=0.f,a1=0.f,a2=0.f,a3=0.f;
  for (int cb=beg; cb<end; cb+=16){
    int n = end-cb; if (n>16) n=16;
    float e = ee[4*cb + lane];          // coalesced; slack-padded
    if (eidx>=n) e = 0.f;
    s_acc += e;
    int jj = cb + (eidx<n ? eidx : n-1);
    int sp = (int)(edge_s[jj].x & 0xffffu);
    uint2 u[8]; float eh[8];
    #pragma unroll
    for (int k=0;k<8;k++){
      int bidx = (2*k + half)<<2;
      int sj = __shfl(sp, bidx);
      eh[k] = __shfl(e, bidx + hF);
      u[k] = *(const uint2*)&feat16[(size_t)sj*64 + li*2];
    }
    #pragma unroll
    for (int k=0;k<8;k++){
      a0 = fmaf(bflo(u[k].x), eh[k], a0);
      a1 = fmaf(bfhi(u[k].x), eh[k], a1);
      a2 = fmaf(bflo(u[k].y), eh[k], a2);
      a3 = fmaf(bfhi(u[k].y), eh[k], a3);
    }
  }
  s_acc += __shfl_xor(s_acc,4);
  s_acc += __shfl_xor(s_acc,8);
  s_acc += __shfl_xor(s_acc,16);
  s_acc += __shfl_xor(s_acc,32);
  float sh = __shfl(s_acc, hF);
  a0 += __shfl_xor(a0,32); a1 += __shfl_xor(a1,32);
  a2 += __shfl_xor(a2,32); a3 += __shfl_xor(a3,32);
  if (half==0){
    float inv = (end>beg)? 1.f/sh : 0.f;
    float4 bv = *(const float4*)&bias[li*4];
    float r0 = a0*inv + bv.x;
    float r1 = a1*inv + bv.y;
    float r2 = a2*inv + bv.z;
    float r3 = a3*inv + bv.w;
    if (!FINAL){
      float4 rs = *(const float4*)&resid[(size_t)node*D + li*4];
      r0 = fmaxf(r0+rs.x, 0.f);
      r1 = fmaxf(r1+rs.y, 0.f);
      r2 = fmaxf(r2+rs.z, 0.f);
      r3 = fmaxf(r3+rs.w, 0.f);
      uint2 o16; o16.x = pack2bf(r0,r1); o16.y = pack2bf(r2,r3);
      *(uint2*)&out16[(size_t)node*64 + li*2] = o16;
    }
    *(float4*)&out[(size_t)node*D + li*4] = make_float4(r0,r1,r2,r3);
  }
}

extern "C" void kernel_launch(void* const* d_in, const int* in_sizes, int n_in,
                              void* d_out, int out_size, void* d_ws, size_t ws_size,
                              hipStream_t stream){
  const float* in_feat = (const float*)d_in[0];
  const float* ew  = (const float*)d_in[1];
  const float* W0  = (const float*)d_in[2];
  const float* al0 = (const float*)d_in[3];
  const float* ar0 = (const float*)d_in[4];
  const float* b0  = (const float*)d_in[5];
  const float* W1  = (const float*)d_in[6];
  const float* al1 = (const float*)d_in[7];
  const float* ar1 = (const float*)d_in[8];
  const float* b1  = (const float*)d_in[9];
  const int* src = (const int*)d_in[10];
  const int* dst = (const int*)d_in[11];
  float* out = (float*)d_out;

  char* p = (char*)d_ws;
  auto alloc = [&](size_t b)->void*{ void* r=(void*)p; p += ((b+255)&~(size_t)255); return r; };
  int*   offs   = (int*)alloc((size_t)(NN+1)*4);
  int*   bcnt   = (int*)alloc((size_t)NB*4);
  int*   boff   = (int*)alloc((size_t)(NB+1)*4);
  int*   bcur   = (int*)alloc((size_t)NB*4);
  uint2* stg    = (uint2*)alloc((size_t)NE*8);
  uint2* edge_s = (uint2*)alloc((size_t)NE*8);
  uint*  h16    = (uint*)alloc((size_t)NN*64*4);          // layer-0 in16, reused as bufC16
  uint*  X16    = (uint*)alloc((size_t)NN*64*4 + 512);    // GEMM input; aliased as ee (NE*4 floats)
  uint*  feat16 = (uint*)alloc((size_t)NN*64*4);
  float* bufC   = (float*)alloc((size_t)NN*D*4);
  uint*  Wt0    = (uint*)alloc((size_t)128*64*4);
  uint*  Wt1    = (uint*)alloc((size_t)128*64*4);
  float* el     = (float*)alloc((size_t)NN*NH*4);
  float* er     = (float*)alloc((size_t)NN*NH*4);
  uint*  gmax0  = (uint*)alloc(16);
  uint*  gmax1  = (uint*)alloc(16);
  uint*  bufC16 = h16;
  float* ee     = (float*)X16;    // alias: X16 consumed by gemm before k_edge writes ee

  hipMemsetAsync(bcnt, 0, (size_t)NB*4, stream);
  hipMemsetAsync(gmax0, 0, 16, stream);
  hipMemsetAsync(gmax1, 0, 16, stream);
  int nsb = (NE + 4095)/4096;  // 196
  k_bhist<<<nsb,256,0,stream>>>(dst, bcnt);
  k_bscan<<<1,512,0,stream>>>(bcnt, boff, bcur);
  k_binscat<<<nsb,256,0,stream>>>(src, dst, ew, bcur, stg);
  k_bfinal<<<NB,256,0,stream>>>(stg, boff, offs, edge_s);
  k_cvt<<<(NN*64+255)/256,256,0,stream>>>(in_feat, h16, NN*64);
  k_cvtW<<<(128*64+255)/256,256,0,stream>>>(W0, Wt0);
  k_cvtW<<<(128*64+255)/256,256,0,stream>>>(W1, Wt1);

  int nwb = (NN*64 + 255)/256; // 12500 blocks (4 waves = 4 nodes each)
  int ngb = (NN+127)/128;      // 391 GEMM blocks
  int neb = (NE*4 + 255)/256;  // 12500 edge-parallel blocks

  // layer 0
  k_wagg<<<nwb,256,0,stream>>>(in_feat, h16, offs, edge_s, X16);
  k_gemm<<<ngb,256,0,stream>>>(X16, Wt0, al0, ar0, feat16, (float4*)el, (float4*)er);
  k_gmax<<<128,256,0,stream>>>((const float4*)el, gmax0);
  k_edge<<<neb,256,0,stream>>>(edge_s, el, er, gmax0, ee);
  k_gat<0><<<nwb,256,0,stream>>>(feat16, ee, edge_s, b0, offs, in_feat, bufC, bufC16);
  // layer 1
  k_wagg<<<nwb,256,0,stream>>>(bufC, bufC16, offs, edge_s, X16);
  k_gemm<<<ngb,256,0,stream>>>(X16, Wt1, al1, ar1, feat16, (float4*)el, (float4*)er);
  k_gmax<<<128,256,0,stream>>>((const float4*)el, gmax1);
  k_edge<<<neb,256,0,stream>>>(edge_s, el, er, gmax1, ee);
  k_gat<1><<<nwb,256,0,stream>>>(feat16, ee, edge_s, b1, offs, nullptr, out, nullptr);
}

// Round 7
// 263.734 us; speedup vs baseline: 2.6809x; 1.1532x over previous
//
#include <hip/hip_runtime.h>

#define NN 50000
#define NE 800000
#define D 128
#define NH 4
#define NB 391   // (NN+127)/128 buckets of 128 nodes

typedef __attribute__((ext_vector_type(8))) short bf16x8;
typedef __attribute__((ext_vector_type(4))) float f32x4;

__device__ __forceinline__ float lrelu(float x){ return x > 0.f ? x : 0.2f*x; }
__device__ __forceinline__ float sel4(int h, float4 v){
  float r = v.x;
  r = (h==1)? v.y : r;
  r = (h==2)? v.z : r;
  r = (h==3)? v.w : r;
  return r;
}
__device__ __forceinline__ ushort f2bf(float f){
  union{ float f; uint i;} v; v.f=f;
  uint r = v.i + 0x7FFFu + ((v.i>>16)&1u);
  return (ushort)(r>>16);
}
__device__ __forceinline__ uint pack2bf(float x, float y){
  return (uint)f2bf(x) | ((uint)f2bf(y)<<16);
}
__device__ __forceinline__ float bflo(uint u){ return __uint_as_float(u<<16); }
__device__ __forceinline__ float bfhi(uint u){ return __uint_as_float(u & 0xffff0000u); }
__device__ __forceinline__ uint encf(float f){
  uint b = __float_as_uint(f);
  return (b & 0x80000000u) ? ~b : (b | 0x80000000u);
}
__device__ __forceinline__ float decf(uint e){
  return (e & 0x80000000u) ? __uint_as_float(e ^ 0x80000000u) : __uint_as_float(~e);
}

// ---------- CSR build: bucket histogram -> scan -> binned scatter -> bucket finalize ----------

__global__ void k_bhist(const int* __restrict__ dst, int* __restrict__ bcnt){
  __shared__ int c[NB];
  int t = threadIdx.x;
  for (int i=t;i<NB;i+=256) c[i]=0;
  __syncthreads();
  int base = blockIdx.x*4096;
  #pragma unroll
  for (int k=0;k<16;k++){
    int i = base + k*256 + t;
    if (i<NE) atomicAdd(&c[dst[i]>>7], 1);
  }
  __syncthreads();
  for (int i=t;i<NB;i+=256){ int v=c[i]; if (v) atomicAdd(&bcnt[i], v); }
}

__global__ void k_bscan(const int* __restrict__ bcnt, int* __restrict__ boff, int* __restrict__ bcur){
  __shared__ int sd[512];
  int t = threadIdx.x;
  int own = (t<NB)? bcnt[t] : 0;
  sd[t] = own;
  __syncthreads();
  for (int off=1; off<512; off<<=1){
    int v = (t>=off)? sd[t-off] : 0;
    __syncthreads();
    sd[t] += v;
    __syncthreads();
  }
  if (t<NB){
    int excl = sd[t]-own;
    boff[t]=excl; bcur[t]=excl;
  }
  if (t==0) boff[NB]=NE;
}

__global__ void k_binscat(const int* __restrict__ src, const int* __restrict__ dst,
                          const float* __restrict__ w, int* __restrict__ bcur,
                          uint2* __restrict__ stg){
  __shared__ int cnt[NB];
  __shared__ int st[NB];
  int t = threadIdx.x;
  for (int i=t;i<NB;i+=256) cnt[i]=0;
  __syncthreads();
  int base = blockIdx.x*4096;
  #pragma unroll
  for (int k=0;k<16;k++){
    int i = base + k*256 + t;
    if (i<NE) atomicAdd(&cnt[dst[i]>>7], 1);
  }
  __syncthreads();
  for (int i=t;i<NB;i+=256){
    int c = cnt[i];
    st[i] = c ? atomicAdd(&bcur[i], c) : 0;
    cnt[i] = 0;
  }
  __syncthreads();
  #pragma unroll
  for (int k=0;k<16;k++){
    int i = base + k*256 + t;
    if (i<NE){
      int d = dst[i];
      int b = d>>7;
      int pos = st[b] + atomicAdd(&cnt[b], 1);
      stg[pos] = make_uint2((uint)src[i] | ((uint)d<<16), __float_as_uint(w[i]));
    }
  }
}

__global__ void k_bfinal(const uint2* __restrict__ stg, const int* __restrict__ boff,
                         int* __restrict__ offs, uint2* __restrict__ edge_s){
  int b = blockIdx.x, t = threadIdx.x;
  int beg = boff[b], end = boff[b+1];
  int node0 = b<<7;
  int nnode = NN - node0; if (nnode>128) nnode=128;
  __shared__ int cnt[128];
  __shared__ int cur[128];
  if (t<128) cnt[t]=0;
  __syncthreads();
  for (int j=beg+t; j<end; j+=256)
    atomicAdd(&cnt[(stg[j].x>>16)&127], 1);
  __syncthreads();
  int own = (t<128)? cnt[t] : 0;
  for (int off=1; off<128; off<<=1){
    int v = (t<128 && t>=off)? cnt[t-off] : 0;
    __syncthreads();
    if (t<128) cnt[t] += v;
    __syncthreads();
  }
  if (t<128){
    int excl = cnt[t]-own;
    cur[t] = beg + excl;
    if (t<nnode) offs[node0+t] = beg + excl;
  }
  if (b==NB-1 && t==0) offs[NN]=NE;
  __syncthreads();
  for (int j=beg+t; j<end; j+=256){
    uint2 v = stg[j];
    int pos = atomicAdd(&cur[(v.x>>16)&127], 1);
    edge_s[pos] = v;
  }
}

// ---------- conversions ----------

__global__ void k_cvt(const float* __restrict__ in, uint* __restrict__ out16, int n2){
  int i = blockIdx.x*256 + threadIdx.x;
  if (i < n2){
    float2 f = *(const float2*)&in[(size_t)i*2];
    out16[i] = pack2bf(f.x, f.y);
  }
}

// W f32 [k=128][n=128] -> Wt bf16 packed [n][k/2 uints]
__global__ void k_cvtW(const float* __restrict__ W, uint* __restrict__ Wt){
  int i = blockIdx.x*256 + threadIdx.x;
  if (i < 128*64){
    int n = i>>6, k2 = i&63;
    float a = W[(size_t)(2*k2)*128 + n];
    float b = W[(size_t)(2*k2+1)*128 + n];
    Wt[i] = pack2bf(a,b);
  }
}

// ---------- weighted aggregation: x[v] = h[v] + sum w_e h[src_e]  (bf16 gather, batched) ----------
// hinF != nullptr: f32 self term; else bf16 self term from hin16
__global__ void k_wagg(const float* __restrict__ hinF, const uint* __restrict__ hin16,
                       const int* __restrict__ offs, const uint2* __restrict__ edge_s,
                       uint* __restrict__ xout16){
  int node = (blockIdx.x*256 + threadIdx.x)>>6;
  int lane = threadIdx.x & 63;
  if (node>=NN) return;
  int beg=offs[node], end=offs[node+1];
  int half = lane>>5, li = lane&31;
  float a0=0.f,a1=0.f,a2=0.f,a3=0.f;
  if (half==0){
    if (hinF){
      float4 s4 = *(const float4*)&hinF[(size_t)node*D + li*4];
      a0=s4.x; a1=s4.y; a2=s4.z; a3=s4.w;
    } else {
      uint2 su = *(const uint2*)&hin16[(size_t)node*64 + li*2];
      a0=bflo(su.x); a1=bfhi(su.x); a2=bflo(su.y); a3=bfhi(su.y);
    }
  }
  for (int cb=beg; cb<end; cb+=64){
    int n = end-cb; if (n>64) n=64;
    int idx = cb + (lane<n ? lane : n-1);
    uint2 ed = edge_s[idx];
    int sp = (int)(ed.x & 0xffffu);
    float wp = __uint_as_float(ed.y);
    int iters = (n+1)>>1;
    for (int i0=0; i0<iters; i0+=8){
      uint2 u[8]; float wk[8];
      #pragma unroll
      for (int k=0;k<8;k++){
        int q = 2*(i0+k) + half;
        int sj = __shfl(sp, q & 63);
        float wq = __shfl(wp, q & 63);
        wk[k] = (q<n)? wq : 0.f;
        u[k] = *(const uint2*)&hin16[(size_t)sj*64 + li*2];
      }
      #pragma unroll
      for (int k=0;k<8;k++){
        a0 = fmaf(bflo(u[k].x), wk[k], a0);
        a1 = fmaf(bfhi(u[k].x), wk[k], a1);
        a2 = fmaf(bflo(u[k].y), wk[k], a2);
        a3 = fmaf(bfhi(u[k].y), wk[k], a3);
      }
    }
  }
  a0 += __shfl_xor(a0,32); a1 += __shfl_xor(a1,32);
  a2 += __shfl_xor(a2,32); a3 += __shfl_xor(a3,32);
  if (half==0){
    uint2 o; o.x = pack2bf(a0,a1); o.y = pack2bf(a2,a3);
    *(uint2*)&xout16[(size_t)node*64 + li*2] = o;
  }
}

// ---------- MFMA GEMM (bf16 in, f32 acc) + fused epilogue: feat16, el/er, global el-max ----------
__global__ __launch_bounds__(256) void k_gemm(const uint* __restrict__ X16, const uint* __restrict__ Wt16,
    const float* __restrict__ al, const float* __restrict__ ar,
    uint* __restrict__ feat16, float4* __restrict__ el4o, float4* __restrict__ er4o,
    uint* __restrict__ gmax_u){
  __shared__ uint sX[128*64];
  __shared__ uint sW[128*64];
  __shared__ float sgm[4][4];
  int t = threadIdx.x;
  int row0 = blockIdx.x*128;
  #pragma unroll
  for (int i=0;i<8;i++){
    int idx = t + 256*i;
    int r = idx>>4, cb = idx&15;
    int gr = row0 + r;
    uint4 v = make_uint4(0u,0u,0u,0u);
    if (gr < NN) v = *(const uint4*)&X16[(size_t)gr*64 + cb*4];
    *(uint4*)&sX[r*64 + ((cb*4) ^ ((r&7)<<2))] = v;
  }
  #pragma unroll
  for (int i=0;i<8;i++){
    int idx = t + 256*i;
    int r = idx>>4, cb = idx&15;
    uint4 v = *(const uint4*)&Wt16[(size_t)r*64 + cb*4];
    *(uint4*)&sW[r*64 + ((cb*4) ^ ((r&7)<<2))] = v;
  }
  __syncthreads();
  int w = t>>6, l = t&63;
  int lr = l&15, lk = l>>4;
  f32x4 acc[2][8];
  #pragma unroll
  for (int rf=0;rf<2;rf++)
    #pragma unroll
    for (int cf=0;cf<8;cf++) acc[rf][cf] = (f32x4){0.f,0.f,0.f,0.f};
  #pragma unroll
  for (int ks=0; ks<4; ks++){
    int cb = ks*4 + lk;
    bf16x8 a[2], b[8];
    #pragma unroll
    for (int rf=0;rf<2;rf++){
      int r = w*32 + rf*16 + lr;
      a[rf] = *(const bf16x8*)&sX[r*64 + ((cb*4) ^ ((r&7)<<2))];
    }
    #pragma unroll
    for (int cf=0;cf<8;cf++){
      int r = cf*16 + lr;
      b[cf] = *(const bf16x8*)&sW[r*64 + ((cb*4) ^ ((r&7)<<2))];
    }
    #pragma unroll
    for (int rf=0;rf<2;rf++)
      #pragma unroll
      for (int cf=0;cf<8;cf++)
        acc[rf][cf] = __builtin_amdgcn_mfma_f32_16x16x32_bf16(a[rf], b[cf], acc[rf][cf], 0,0,0);
  }
  float al_v[8], ar_v[8];
  #pragma unroll
  for (int cf=0;cf<8;cf++){ al_v[cf]=al[cf*16+lr]; ar_v[cf]=ar[cf*16+lr]; }
  float gm0=-3e38f,gm1=-3e38f,gm2=-3e38f,gm3=-3e38f;
  #pragma unroll
  for (int rf=0;rf<2;rf++){
    #pragma unroll
    for (int reg=0;reg<4;reg++){
      int grow = row0 + w*32 + rf*16 + lk*4 + reg;
      float eh[4]={0.f,0.f,0.f,0.f}, fh[4]={0.f,0.f,0.f,0.f};
      #pragma unroll
      for (int cf=0;cf<8;cf++){
        float v = acc[rf][cf][reg];
        eh[cf>>1] = fmaf(v, al_v[cf], eh[cf>>1]);
        fh[cf>>1] = fmaf(v, ar_v[cf], fh[cf>>1]);
      }
      #pragma unroll
      for (int off=1; off<16; off<<=1){
        #pragma unroll
        for (int h=0;h<4;h++){
          eh[h] += __shfl_xor(eh[h], off);
          fh[h] += __shfl_xor(fh[h], off);
        }
      }
      if (lr==0 && grow<NN){
        el4o[grow] = make_float4(eh[0],eh[1],eh[2],eh[3]);
        er4o[grow] = make_float4(fh[0],fh[1],fh[2],fh[3]);
      }
      if (grow<NN){
        gm0=fmaxf(gm0,eh[0]); gm1=fmaxf(gm1,eh[1]);
        gm2=fmaxf(gm2,eh[2]); gm3=fmaxf(gm3,eh[3]);
      }
      #pragma unroll
      for (int cf=0;cf<8;cf++){
        float v = acc[rf][cf][reg];
        float pv = __shfl_xor(v, 1);
        if (!(lr&1) && grow<NN)
          feat16[(size_t)grow*64 + ((cf*16+lr)>>1)] = pack2bf(v, pv);
      }
    }
  }
  // block-level el max -> global atomic
  #pragma unroll
  for (int off=1; off<64; off<<=1){
    gm0=fmaxf(gm0,__shfl_xor(gm0,off));
    gm1=fmaxf(gm1,__shfl_xor(gm1,off));
    gm2=fmaxf(gm2,__shfl_xor(gm2,off));
    gm3=fmaxf(gm3,__shfl_xor(gm3,off));
  }
  if (l==0){ sgm[w][0]=gm0; sgm[w][1]=gm1; sgm[w][2]=gm2; sgm[w][3]=gm3; }
  __syncthreads();
  if (t==0){
    float m0=fmaxf(fmaxf(sgm[0][0],sgm[1][0]),fmaxf(sgm[2][0],sgm[3][0]));
    float m1=fmaxf(fmaxf(sgm[0][1],sgm[1][1]),fmaxf(sgm[2][1],sgm[3][1]));
    float m2=fmaxf(fmaxf(sgm[0][2],sgm[1][2]),fmaxf(sgm[2][2],sgm[3][2]));
    float m3=fmaxf(fmaxf(sgm[0][3],sgm[1][3]),fmaxf(sgm[2][3],sgm[3][3]));
    atomicMax(&gmax_u[0], encf(m0));
    atomicMax(&gmax_u[1], encf(m1));
    atomicMax(&gmax_u[2], encf(m2));
    atomicMax(&gmax_u[3], encf(m3));
  }
}

// ---------- GAT edge-softmax + aggregation (bf16 feat gather, inline exp) ----------
// FINAL=0: out16 = bf16(relu(rst+b+resid));  FINAL=1: outF = rst+b
template<int FINAL>
__global__ void k_gat(const uint* __restrict__ feat16, const float4* __restrict__ el4,
                      const float4* __restrict__ er4, const uint* __restrict__ gmax_u,
                      const float* __restrict__ bias, const int* __restrict__ offs,
                      const uint2* __restrict__ edge_s, const float* __restrict__ resid,
                      float* __restrict__ outF, uint* __restrict__ out16){
  int node = (blockIdx.x*256 + threadIdx.x)>>6;
  int lane = threadIdx.x & 63;
  if (node>=NN) return;
  int beg=offs[node], end=offs[node+1];
  int half = lane>>5, li = lane&31;
  int hF = li>>3;           // head of this lane's 4 columns
  int hp = lane & 3;        // head this lane's exp covers
  int eidx = lane>>2;
  float4 erv = er4[node];
  uint4 g = *(const uint4*)gmax_u;
  float4 m4 = make_float4(lrelu(decf(g.x)+erv.x), lrelu(decf(g.y)+erv.y),
                          lrelu(decf(g.z)+erv.z), lrelu(decf(g.w)+erv.w));
  float mh  = sel4(hp, m4);
  float erh = sel4(hp, erv);
  float s_acc = 0.f;
  float a0=0.f,a1=0.f,a2=0.f,a3=0.f;
  for (int cb=beg; cb<end; cb+=16){
    int n = end-cb; if (n>16) n=16;
    int jj = cb + (eidx<n ? eidx : n-1);
    uint2 ed = edge_s[jj];
    int sp = (int)(ed.x & 0xffffu);
    float4 ev = el4[sp];
    float e = __expf(lrelu(sel4(hp,ev)+erh) - mh);
    e = (eidx<n) ? e : 0.f;
    s_acc += e;
    uint2 u[8]; float eh[8];
    #pragma unroll
    for (int k=0;k<8;k++){
      int bidx = (2*k + half)<<2;
      int sj = __shfl(sp, bidx);
      eh[k] = __shfl(e, bidx + hF);
      u[k] = *(const uint2*)&feat16[(size_t)sj*64 + li*2];
    }
    #pragma unroll
    for (int k=0;k<8;k++){
      a0 = fmaf(bflo(u[k].x), eh[k], a0);
      a1 = fmaf(bfhi(u[k].x), eh[k], a1);
      a2 = fmaf(bflo(u[k].y), eh[k], a2);
      a3 = fmaf(bfhi(u[k].y), eh[k], a3);
    }
  }
  s_acc += __shfl_xor(s_acc,4);
  s_acc += __shfl_xor(s_acc,8);
  s_acc += __shfl_xor(s_acc,16);
  s_acc += __shfl_xor(s_acc,32);
  float sh = __shfl(s_acc, hF);
  a0 += __shfl_xor(a0,32); a1 += __shfl_xor(a1,32);
  a2 += __shfl_xor(a2,32); a3 += __shfl_xor(a3,32);
  if (half==0){
    float inv = (end>beg)? 1.f/sh : 0.f;
    float4 bv = *(const float4*)&bias[li*4];
    float r0 = a0*inv + bv.x;
    float r1 = a1*inv + bv.y;
    float r2 = a2*inv + bv.z;
    float r3 = a3*inv + bv.w;
    if (FINAL==0){
      float4 rs = *(const float4*)&resid[(size_t)node*D + li*4];
      r0 = fmaxf(r0+rs.x, 0.f);
      r1 = fmaxf(r1+rs.y, 0.f);
      r2 = fmaxf(r2+rs.z, 0.f);
      r3 = fmaxf(r3+rs.w, 0.f);
      uint2 o16; o16.x = pack2bf(r0,r1); o16.y = pack2bf(r2,r3);
      *(uint2*)&out16[(size_t)node*64 + li*2] = o16;
    } else {
      *(float4*)&outF[(size_t)node*D + li*4] = make_float4(r0,r1,r2,r3);
    }
  }
}

extern "C" void kernel_launch(void* const* d_in, const int* in_sizes, int n_in,
                              void* d_out, int out_size, void* d_ws, size_t ws_size,
                              hipStream_t stream){
  const float* in_feat = (const float*)d_in[0];
  const float* ew  = (const float*)d_in[1];
  const float* W0  = (const float*)d_in[2];
  const float* al0 = (const float*)d_in[3];
  const float* ar0 = (const float*)d_in[4];
  const float* b0  = (const float*)d_in[5];
  const float* W1  = (const float*)d_in[6];
  const float* al1 = (const float*)d_in[7];
  const float* ar1 = (const float*)d_in[8];
  const float* b1  = (const float*)d_in[9];
  const int* src = (const int*)d_in[10];
  const int* dst = (const int*)d_in[11];
  float* out = (float*)d_out;

  char* p = (char*)d_ws;
  auto alloc = [&](size_t b)->void*{ void* r=(void*)p; p += ((b+255)&~(size_t)255); return r; };
  int*   offs   = (int*)alloc((size_t)(NN+1)*4);
  int*   bcnt   = (int*)alloc((size_t)NB*4);
  int*   boff   = (int*)alloc((size_t)(NB+1)*4);
  int*   bcur   = (int*)alloc((size_t)NB*4);
  uint2* stg    = (uint2*)alloc((size_t)NE*8);
  uint2* edge_s = (uint2*)alloc((size_t)NE*8);
  uint*  h16    = (uint*)alloc((size_t)NN*64*4);   // layer input bf16; overwritten by k_gat<0> as layer-0 out
  uint*  x16    = (uint*)alloc((size_t)NN*64*4);   // post-wagg bf16 (GEMM input)
  uint*  feat16 = (uint*)alloc((size_t)NN*64*4);   // bf16 feat for gather
  uint*  Wt0    = (uint*)alloc((size_t)128*64*4);
  uint*  Wt1    = (uint*)alloc((size_t)128*64*4);
  float* el     = (float*)alloc((size_t)NN*NH*4);
  float* er     = (float*)alloc((size_t)NN*NH*4);
  uint*  gmax0  = (uint*)alloc(16);
  uint*  gmax1  = (uint*)alloc(16);

  hipMemsetAsync(bcnt, 0, (size_t)NB*4, stream);
  hipMemsetAsync(gmax0, 0, 16, stream);
  hipMemsetAsync(gmax1, 0, 16, stream);
  int nsb = (NE + 4095)/4096;  // 196
  k_bhist<<<nsb,256,0,stream>>>(dst, bcnt);
  k_bscan<<<1,512,0,stream>>>(bcnt, boff, bcur);
  k_binscat<<<nsb,256,0,stream>>>(src, dst, ew, bcur, stg);
  k_bfinal<<<NB,256,0,stream>>>(stg, boff, offs, edge_s);
  k_cvt<<<(NN*64+255)/256,256,0,stream>>>(in_feat, h16, NN*64);
  k_cvtW<<<(128*64+255)/256,256,0,stream>>>(W0, Wt0);
  k_cvtW<<<(128*64+255)/256,256,0,stream>>>(W1, Wt1);

  int nwb = (NN*64 + 255)/256; // 12500 blocks (4 waves = 4 nodes each)
  int ngb = (NN+127)/128;      // 391 GEMM blocks

  // layer 0
  k_wagg<<<nwb,256,0,stream>>>(in_feat, h16, offs, edge_s, x16);
  k_gemm<<<ngb,256,0,stream>>>(x16, Wt0, al0, ar0, feat16, (float4*)el, (float4*)er, gmax0);
  k_gat<0><<<nwb,256,0,stream>>>(feat16, (const float4*)el, (const float4*)er, gmax0, b0,
                                 offs, edge_s, in_feat, nullptr, h16);
  // layer 1
  k_wagg<<<nwb,256,0,stream>>>(nullptr, h16, offs, edge_s, x16);
  k_gemm<<<ngb,256,0,stream>>>(x16, Wt1, al1, ar1, feat16, (float4*)el, (float4*)er, gmax1);
  k_gat<1><<<nwb,256,0,stream>>>(feat16, (const float4*)el, (const float4*)er, gmax1, b1,
                                 offs, edge_s, nullptr, out, nullptr);
}

// Round 8
// 233.498 us; speedup vs baseline: 3.0281x; 1.1295x over previous
//
#include <hip/hip_runtime.h>

#define NN 50000
#define NE 800000
#define D 128
#define NH 4
#define NB 391   // (NN+127)/128 buckets of 128 nodes

typedef __attribute__((ext_vector_type(8))) short bf16x8;
typedef __attribute__((ext_vector_type(4))) float f32x4;

__device__ __forceinline__ float lrelu(float x){ return x > 0.f ? x : 0.2f*x; }
__device__ __forceinline__ float sel4(int h, float4 v){
  float r = v.x;
  r = (h==1)? v.y : r;
  r = (h==2)? v.z : r;
  r = (h==3)? v.w : r;
  return r;
}
__device__ __forceinline__ ushort f2bf(float f){
  union{ float f; uint i;} v; v.f=f;
  uint r = v.i + 0x7FFFu + ((v.i>>16)&1u);
  return (ushort)(r>>16);
}
__device__ __forceinline__ uint pack2bf(float x, float y){
  return (uint)f2bf(x) | ((uint)f2bf(y)<<16);
}
__device__ __forceinline__ float bflo(uint u){ return __uint_as_float(u<<16); }
__device__ __forceinline__ float bfhi(uint u){ return __uint_as_float(u & 0xffff0000u); }
__device__ __forceinline__ uint encf(float f){
  uint b = __float_as_uint(f);
  return (b & 0x80000000u) ? ~b : (b | 0x80000000u);
}
__device__ __forceinline__ float decf(uint e){
  return (e & 0x80000000u) ? __uint_as_float(e ^ 0x80000000u) : __uint_as_float(~e);
}

// ---------- CSR build: bucket histogram -> scan -> binned scatter -> bucket finalize ----------

__global__ void k_bhist(const int* __restrict__ dst, int* __restrict__ bcnt){
  __shared__ int c[NB];
  int t = threadIdx.x;
  for (int i=t;i<NB;i+=256) c[i]=0;
  __syncthreads();
  int base = blockIdx.x*4096;
  #pragma unroll
  for (int k=0;k<16;k++){
    int i = base + k*256 + t;
    if (i<NE) atomicAdd(&c[dst[i]>>7], 1);
  }
  __syncthreads();
  for (int i=t;i<NB;i+=256){ int v=c[i]; if (v) atomicAdd(&bcnt[i], v); }
}

__global__ void k_bscan(const int* __restrict__ bcnt, int* __restrict__ boff, int* __restrict__ bcur){
  __shared__ int sd[512];
  int t = threadIdx.x;
  int own = (t<NB)? bcnt[t] : 0;
  sd[t] = own;
  __syncthreads();
  for (int off=1; off<512; off<<=1){
    int v = (t>=off)? sd[t-off] : 0;
    __syncthreads();
    sd[t] += v;
    __syncthreads();
  }
  if (t<NB){
    int excl = sd[t]-own;
    boff[t]=excl; bcur[t]=excl;
  }
  if (t==0) boff[NB]=NE;
}

__global__ void k_binscat(const int* __restrict__ src, const int* __restrict__ dst,
                          const float* __restrict__ w, int* __restrict__ bcur,
                          uint2* __restrict__ stg){
  __shared__ int cnt[NB];
  __shared__ int st[NB];
  int t = threadIdx.x;
  for (int i=t;i<NB;i+=256) cnt[i]=0;
  __syncthreads();
  int base = blockIdx.x*4096;
  #pragma unroll
  for (int k=0;k<16;k++){
    int i = base + k*256 + t;
    if (i<NE) atomicAdd(&cnt[dst[i]>>7], 1);
  }
  __syncthreads();
  for (int i=t;i<NB;i+=256){
    int c = cnt[i];
    st[i] = c ? atomicAdd(&bcur[i], c) : 0;
    cnt[i] = 0;
  }
  __syncthreads();
  #pragma unroll
  for (int k=0;k<16;k++){
    int i = base + k*256 + t;
    if (i<NE){
      int d = dst[i];
      int b = d>>7;
      int pos = st[b] + atomicAdd(&cnt[b], 1);
      stg[pos] = make_uint2((uint)src[i] | ((uint)d<<16), __float_as_uint(w[i]));
    }
  }
}

__global__ void k_bfinal(const uint2* __restrict__ stg, const int* __restrict__ boff,
                         int* __restrict__ offs, uint2* __restrict__ edge_s){
  int b = blockIdx.x, t = threadIdx.x;
  int beg = boff[b], end = boff[b+1];
  int node0 = b<<7;
  int nnode = NN - node0; if (nnode>128) nnode=128;
  __shared__ int cnt[128];
  __shared__ int cur[128];
  if (t<128) cnt[t]=0;
  __syncthreads();
  for (int j=beg+t; j<end; j+=256)
    atomicAdd(&cnt[(stg[j].x>>16)&127], 1);
  __syncthreads();
  int own = (t<128)? cnt[t] : 0;
  for (int off=1; off<128; off<<=1){
    int v = (t<128 && t>=off)? cnt[t-off] : 0;
    __syncthreads();
    if (t<128) cnt[t] += v;
    __syncthreads();
  }
  if (t<128){
    int excl = cnt[t]-own;
    cur[t] = beg + excl;
    if (t<nnode) offs[node0+t] = beg + excl;
  }
  if (b==NB-1 && t==0) offs[NN]=NE;
  __syncthreads();
  for (int j=beg+t; j<end; j+=256){
    uint2 v = stg[j];
    int pos = atomicAdd(&cur[(v.x>>16)&127], 1);
    edge_s[pos] = v;
  }
}

// ---------- conversions / prep ----------

__global__ void k_cvt(const float* __restrict__ in, uint* __restrict__ out16, int n2){
  int i = blockIdx.x*256 + threadIdx.x;
  if (i < n2){
    float2 f = *(const float2*)&in[(size_t)i*2];
    out16[i] = pack2bf(f.x, f.y);
  }
}

// W f32 [k=128][n=128] -> Wtaug rows 0..127: bf16 packed [n][k/2 uints]
__global__ void k_cvtW(const float* __restrict__ W, uint* __restrict__ Wt){
  int i = blockIdx.x*256 + threadIdx.x;
  if (i < 128*64){
    int n = i>>6, k2 = i&63;
    float a = W[(size_t)(2*k2)*128 + n];
    float b = W[(size_t)(2*k2+1)*128 + n];
    Wt[i] = pack2bf(a,b);
  }
}

// rows 128..135 of Wtaug: Wal[k][h] = sum_i W[k][h*32+i]*a[h*32+i] (el/er projection vectors)
__global__ void k_prep(const float* __restrict__ W0, const float* __restrict__ al0,
                       const float* __restrict__ ar0, const float* __restrict__ W1,
                       const float* __restrict__ al1, const float* __restrict__ ar1,
                       uint* __restrict__ aug0, uint* __restrict__ aug1){
  __shared__ float sv[128][4];
  int b = blockIdx.x, t = threadIdx.x;   // 512 threads
  const float* W = (b<2)? W0 : W1;
  const float* a = (b==0)? al0 : (b==1)? ar0 : (b==2)? al1 : ar1;
  uint* o = (b<2)? aug0 : aug1;
  int rbase = (b&1)? 132 : 128;
  int d = t>>2, h = t&3;
  float s = 0.f;
  #pragma unroll
  for (int i=0;i<32;i++) s += W[d*128 + h*32 + i] * a[h*32 + i];
  sv[d][h] = s;
  __syncthreads();
  if (t<256){
    int h2 = t>>6, k2 = t&63;
    o[(rbase+h2)*64 + k2] = pack2bf(sv[2*k2][h2], sv[2*k2+1][h2]);
  }
}

// ---------- weighted aggregation: x[v] = h[v] + sum w_e h[src_e]  (bf16 gather, batched) ----------
__global__ void k_wagg(const float* __restrict__ hinF, const uint* __restrict__ hin16,
                       const int* __restrict__ offs, const uint2* __restrict__ edge_s,
                       uint* __restrict__ xout16){
  int node = (blockIdx.x*256 + threadIdx.x)>>6;
  int lane = threadIdx.x & 63;
  if (node>=NN) return;
  int beg=offs[node], end=offs[node+1];
  int half = lane>>5, li = lane&31;
  float a0=0.f,a1=0.f,a2=0.f,a3=0.f;
  if (half==0){
    if (hinF){
      float4 s4 = *(const float4*)&hinF[(size_t)node*D + li*4];
      a0=s4.x; a1=s4.y; a2=s4.z; a3=s4.w;
    } else {
      uint2 su = *(const uint2*)&hin16[(size_t)node*64 + li*2];
      a0=bflo(su.x); a1=bfhi(su.x); a2=bflo(su.y); a3=bfhi(su.y);
    }
  }
  for (int cb=beg; cb<end; cb+=64){
    int n = end-cb; if (n>64) n=64;
    int idx = cb + (lane<n ? lane : n-1);
    uint2 ed = edge_s[idx];
    int sp = (int)(ed.x & 0xffffu);
    float wp = __uint_as_float(ed.y);
    int iters = (n+1)>>1;
    for (int i0=0; i0<iters; i0+=8){
      uint2 u[8]; float wk[8];
      #pragma unroll
      for (int k=0;k<8;k++){
        int q = 2*(i0+k) + half;
        int sj = __shfl(sp, q & 63);
        float wq = __shfl(wp, q & 63);
        wk[k] = (q<n)? wq : 0.f;
        u[k] = *(const uint2*)&hin16[(size_t)sj*64 + li*2];
      }
      #pragma unroll
      for (int k=0;k<8;k++){
        a0 = fmaf(bflo(u[k].x), wk[k], a0);
        a1 = fmaf(bfhi(u[k].x), wk[k], a1);
        a2 = fmaf(bflo(u[k].y), wk[k], a2);
        a3 = fmaf(bfhi(u[k].y), wk[k], a3);
      }
    }
  }
  a0 += __shfl_xor(a0,32); a1 += __shfl_xor(a1,32);
  a2 += __shfl_xor(a2,32); a3 += __shfl_xor(a3,32);
  if (half==0){
    uint2 o; o.x = pack2bf(a0,a1); o.y = pack2bf(a2,a3);
    *(uint2*)&xout16[(size_t)node*64 + li*2] = o;
  }
}

// ---------- MFMA GEMM (bf16 in, f32 acc), aug columns give el/er; shuffle-free epilogue ----------
__global__ __launch_bounds__(256) void k_gemm(const uint* __restrict__ X16, const uint* __restrict__ Wtaug,
    uint* __restrict__ feat16, float* __restrict__ el, float* __restrict__ er,
    uint* __restrict__ gmax_u){
  __shared__ uint sX[128*64];
  __shared__ uint sW[144*64];
  __shared__ float sgm[4][4];
  int t = threadIdx.x;
  int row0 = blockIdx.x*128;
  #pragma unroll
  for (int i=0;i<8;i++){
    int idx = t + 256*i;
    int r = idx>>4, cb = idx&15;
    int gr = row0 + r;
    uint4 v = make_uint4(0u,0u,0u,0u);
    if (gr < NN) v = *(const uint4*)&X16[(size_t)gr*64 + cb*4];
    *(uint4*)&sX[r*64 + ((cb*4) ^ ((r&7)<<2))] = v;
  }
  #pragma unroll
  for (int i=0;i<9;i++){
    int idx = t + 256*i;            // 0..2303 -> 144 rows
    int r = idx>>4, cb = idx&15;
    uint4 v = *(const uint4*)&Wtaug[(size_t)r*64 + cb*4];
    *(uint4*)&sW[r*64 + ((cb*4) ^ ((r&7)<<2))] = v;
  }
  __syncthreads();
  int w = t>>6, l = t&63;
  int lr = l&15, lk = l>>4;
  f32x4 acc[2][8];
  f32x4 acc_e[2];
  #pragma unroll
  for (int rf=0;rf<2;rf++){
    acc_e[rf] = (f32x4){0.f,0.f,0.f,0.f};
    #pragma unroll
    for (int cf=0;cf<8;cf++) acc[rf][cf] = (f32x4){0.f,0.f,0.f,0.f};
  }
  #pragma unroll
  for (int ks=0; ks<4; ks++){
    int cb = ks*4 + lk;
    bf16x8 a[2], b[8], baug;
    #pragma unroll
    for (int rf=0;rf<2;rf++){
      int r = w*32 + rf*16 + lr;
      a[rf] = *(const bf16x8*)&sX[r*64 + ((cb*4) ^ ((r&7)<<2))];
    }
    #pragma unroll
    for (int cf=0;cf<8;cf++){
      int r = cf*16 + lr;
      b[cf] = *(const bf16x8*)&sW[r*64 + ((cb*4) ^ ((r&7)<<2))];
    }
    {
      int r = 128 + lr;
      baug = *(const bf16x8*)&sW[r*64 + ((cb*4) ^ ((r&7)<<2))];
    }
    #pragma unroll
    for (int rf=0;rf<2;rf++){
      #pragma unroll
      for (int cf=0;cf<8;cf++)
        acc[rf][cf] = __builtin_amdgcn_mfma_f32_16x16x32_bf16(a[rf], b[cf], acc[rf][cf], 0,0,0);
      acc_e[rf] = __builtin_amdgcn_mfma_f32_16x16x32_bf16(a[rf], baug, acc_e[rf], 0,0,0);
    }
  }
  // epilogue: zero cross-lane traffic (2-byte feat stores, direct el/er stores)
  ushort* f16s = (ushort*)feat16;
  float gm = -3e38f;
  #pragma unroll
  for (int rf=0;rf<2;rf++){
    #pragma unroll
    for (int reg=0;reg<4;reg++){
      int grow = row0 + w*32 + rf*16 + lk*4 + reg;
      if (grow < NN){
        #pragma unroll
        for (int cf=0;cf<8;cf++)
          f16s[(size_t)grow*128 + cf*16 + lr] = f2bf(acc[rf][cf][reg]);
        float v = acc_e[rf][reg];
        if (lr<4){ el[grow*4 + lr] = v; gm = fmaxf(gm, v); }
        else if (lr<8){ er[grow*4 + lr-4] = v; }
      }
    }
  }
  gm = fmaxf(gm, __shfl_xor(gm,16));
  gm = fmaxf(gm, __shfl_xor(gm,32));
  if (l<4) sgm[w][l] = gm;
  __syncthreads();
  if (t<4){
    float m = fmaxf(fmaxf(sgm[0][t],sgm[1][t]), fmaxf(sgm[2][t],sgm[3][t]));
    atomicMax(&gmax_u[t], encf(m));
  }
}

// ---------- GAT edge-softmax + aggregation (bf16 feat gather, inline exp) ----------
// FINAL=0: out16 = bf16(relu(rst+b+resid));  FINAL=1: outF = rst+b
template<int FINAL>
__global__ void k_gat(const uint* __restrict__ feat16, const float4* __restrict__ el4,
                      const float4* __restrict__ er4, const uint* __restrict__ gmax_u,
                      const float* __restrict__ bias, const int* __restrict__ offs,
                      const uint2* __restrict__ edge_s, const float* __restrict__ resid,
                      float* __restrict__ outF, uint* __restrict__ out16){
  int node = (blockIdx.x*256 + threadIdx.x)>>6;
  int lane = threadIdx.x & 63;
  if (node>=NN) return;
  int beg=offs[node], end=offs[node+1];
  int half = lane>>5, li = lane&31;
  int hF = li>>3;           // head of this lane's 4 columns
  int hp = lane & 3;        // head this lane's exp covers
  int eidx = lane>>2;
  float4 erv = er4[node];
  uint4 g = *(const uint4*)gmax_u;
  float4 m4 = make_float4(lrelu(decf(g.x)+erv.x), lrelu(decf(g.y)+erv.y),
                          lrelu(decf(g.z)+erv.z), lrelu(decf(g.w)+erv.w));
  float mh  = sel4(hp, m4);
  float erh = sel4(hp, erv);
  float s_acc = 0.f;
  float a0=0.f,a1=0.f,a2=0.f,a3=0.f;
  for (int cb=beg; cb<end; cb+=16){
    int n = end-cb; if (n>16) n=16;
    int jj = cb + (eidx<n ? eidx : n-1);
    uint2 ed = edge_s[jj];
    int sp = (int)(ed.x & 0xffffu);
    float4 ev = el4[sp];
    float e = __expf(lrelu(sel4(hp,ev)+erh) - mh);
    e = (eidx<n) ? e : 0.f;
    s_acc += e;
    uint2 u[8]; float eh[8];
    #pragma unroll
    for (int k=0;k<8;k++){
      int bidx = (2*k + half)<<2;
      int sj = __shfl(sp, bidx);
      eh[k] = __shfl(e, bidx + hF);
      u[k] = *(const uint2*)&feat16[(size_t)sj*64 + li*2];
    }
    #pragma unroll
    for (int k=0;k<8;k++){
      a0 = fmaf(bflo(u[k].x), eh[k], a0);
      a1 = fmaf(bfhi(u[k].x), eh[k], a1);
      a2 = fmaf(bflo(u[k].y), eh[k], a2);
      a3 = fmaf(bfhi(u[k].y), eh[k], a3);
    }
  }
  s_acc += __shfl_xor(s_acc,4);
  s_acc += __shfl_xor(s_acc,8);
  s_acc += __shfl_xor(s_acc,16);
  s_acc += __shfl_xor(s_acc,32);
  float sh = __shfl(s_acc, hF);
  a0 += __shfl_xor(a0,32); a1 += __shfl_xor(a1,32);
  a2 += __shfl_xor(a2,32); a3 += __shfl_xor(a3,32);
  if (half==0){
    float inv = (end>beg)? 1.f/sh : 0.f;
    float4 bv = *(const float4*)&bias[li*4];
    float r0 = a0*inv + bv.x;
    float r1 = a1*inv + bv.y;
    float r2 = a2*inv + bv.z;
    float r3 = a3*inv + bv.w;
    if (FINAL==0){
      float4 rs = *(const float4*)&resid[(size_t)node*D + li*4];
      r0 = fmaxf(r0+rs.x, 0.f);
      r1 = fmaxf(r1+rs.y, 0.f);
      r2 = fmaxf(r2+rs.z, 0.f);
      r3 = fmaxf(r3+rs.w, 0.f);
      uint2 o16; o16.x = pack2bf(r0,r1); o16.y = pack2bf(r2,r3);
      *(uint2*)&out16[(size_t)node*64 + li*2] = o16;
    } else {
      *(float4*)&outF[(size_t)node*D + li*4] = make_float4(r0,r1,r2,r3);
    }
  }
}

extern "C" void kernel_launch(void* const* d_in, const int* in_sizes, int n_in,
                              void* d_out, int out_size, void* d_ws, size_t ws_size,
                              hipStream_t stream){
  const float* in_feat = (const float*)d_in[0];
  const float* ew  = (const float*)d_in[1];
  const float* W0  = (const float*)d_in[2];
  const float* al0 = (const float*)d_in[3];
  const float* ar0 = (const float*)d_in[4];
  const float* b0  = (const float*)d_in[5];
  const float* W1  = (const float*)d_in[6];
  const float* al1 = (const float*)d_in[7];
  const float* ar1 = (const float*)d_in[8];
  const float* b1  = (const float*)d_in[9];
  const int* src = (const int*)d_in[10];
  const int* dst = (const int*)d_in[11];
  float* out = (float*)d_out;

  char* p = (char*)d_ws;
  auto alloc = [&](size_t b)->void*{ void* r=(void*)p; p += ((b+255)&~(size_t)255); return r; };
  int*   offs   = (int*)alloc((size_t)(NN+1)*4);
  int*   bcnt   = (int*)alloc((size_t)NB*4);
  int*   boff   = (int*)alloc((size_t)(NB+1)*4);
  int*   bcur   = (int*)alloc((size_t)NB*4);
  uint2* stg    = (uint2*)alloc((size_t)NE*8);
  uint2* edge_s = (uint2*)alloc((size_t)NE*8);
  uint*  h16    = (uint*)alloc((size_t)NN*64*4);   // layer input bf16; overwritten by k_gat<0>
  uint*  x16    = (uint*)alloc((size_t)NN*64*4);   // post-wagg bf16 (GEMM input)
  uint*  feat16 = (uint*)alloc((size_t)NN*64*4);   // bf16 feat for gather
  uint*  Wt0    = (uint*)alloc((size_t)144*64*4);  // augmented: rows 0-127 W, 128-135 Wal/War, 136-143 zero
  uint*  Wt1    = (uint*)alloc((size_t)144*64*4);
  float* el     = (float*)alloc((size_t)NN*NH*4);
  float* er     = (float*)alloc((size_t)NN*NH*4);
  uint*  gmax0  = (uint*)alloc(16);
  uint*  gmax1  = (uint*)alloc(16);

  hipMemsetAsync(bcnt, 0, (size_t)NB*4, stream);
  hipMemsetAsync(gmax0, 0, 16, stream);
  hipMemsetAsync(gmax1, 0, 16, stream);
  hipMemsetAsync(Wt0, 0, (size_t)144*64*4, stream);
  hipMemsetAsync(Wt1, 0, (size_t)144*64*4, stream);
  int nsb = (NE + 4095)/4096;  // 196
  k_bhist<<<nsb,256,0,stream>>>(dst, bcnt);
  k_bscan<<<1,512,0,stream>>>(bcnt, boff, bcur);
  k_binscat<<<nsb,256,0,stream>>>(src, dst, ew, bcur, stg);
  k_bfinal<<<NB,256,0,stream>>>(stg, boff, offs, edge_s);
  k_cvt<<<(NN*64+255)/256,256,0,stream>>>(in_feat, h16, NN*64);
  k_cvtW<<<(128*64+255)/256,256,0,stream>>>(W0, Wt0);
  k_cvtW<<<(128*64+255)/256,256,0,stream>>>(W1, Wt1);
  k_prep<<<4,512,0,stream>>>(W0, al0, ar0, W1, al1, ar1, Wt0, Wt1);

  int nwb = (NN*64 + 255)/256; // 12500 blocks (4 waves = 4 nodes each)
  int ngb = (NN+127)/128;      // 391 GEMM blocks

  // layer 0
  k_wagg<<<nwb,256,0,stream>>>(in_feat, h16, offs, edge_s, x16);
  k_gemm<<<ngb,256,0,stream>>>(x16, Wt0, feat16, el, er, gmax0);
  k_gat<0><<<nwb,256,0,stream>>>(feat16, (const float4*)el, (const float4*)er, gmax0, b0,
                                 offs, edge_s, in_feat, nullptr, h16);
  // layer 1
  k_wagg<<<nwb,256,0,stream>>>(nullptr, h16, offs, edge_s, x16);
  k_gemm<<<ngb,256,0,stream>>>(x16, Wt1, feat16, el, er, gmax1);
  k_gat<1><<<nwb,256,0,stream>>>(feat16, (const float4*)el, (const float4*)er, gmax1, b1,
                                 offs, edge_s, nullptr, out, nullptr);
}